// Round 6
// baseline (628.279 us; speedup 1.0000x reference)
//
#include <hip/hip_runtime.h>
#include <hip/hip_bf16.h>
#include <cstdint>
#include <cstddef>

typedef __attribute__((ext_vector_type(8))) short short8;
typedef __attribute__((ext_vector_type(4))) float f32x4;
typedef __attribute__((ext_vector_type(2))) float f32x2;
typedef unsigned short ushort_t;

// ---------------- ws layout (bytes) ----------------
#define WBF_OFF   0u            // 512*64*64 bf16 (linear) = 4 MiB
#define KVH_OFF   4194304u      // 32768*128 bf16 (kh|vh per row) = 8 MiB
#define QH_OFF    12582912u     // 512*64 f32 (pre-scaled by 1/sqrt(8))
#define AVG_OFF   12713984u     // 512*64 f32 row means of mem_w
#define WEFF_OFF  12845056u     // 3 * 64*64 f32 combined projections
#define BEFF_OFF  12894208u     // 3 * 64 f32 combined biases
#define OACC_OFF  12894976u     // 8*512*8 f32 attention numerator
#define ESUM_OFF  13026048u     // 8*512 f32 softmax denominator
#define RATIO_OFF 13042432u     // 512*64 f32 (1 + attn_out/row_mean)
#define FLAG_OFF  13173504u     // int: nontrivial ln_g/ln_b flag
#define PO_OFF    13180928u     // 64 chunks * 32768 f32 partial O = 8 MiB
#define PE_OFF    21569536u     // 64 chunks * 4096 f32 partial esum = 1 MiB
#define WS_NEED   22618112ull   // bytes required for the partial scheme
#define NCH 64                  // key chunks (512 keys each)

__device__ __forceinline__ float bf2f(ushort_t u) {
  union { unsigned int i; float f; } c; c.i = ((unsigned int)u) << 16; return c.f;
}
__device__ __forceinline__ unsigned pk2bf(float a, float b) {
  __hip_bfloat162 h = __float22bfloat162_rn(make_float2(a, b));
  unsigned u;
  __builtin_memcpy(&u, &h, 4);
  return u;
}
__device__ __forceinline__ ushort_t f2bf1(float f) {
  union { float f; unsigned int i; } c; c.f = f;
  unsigned int x = c.i;
  x += 0x7FFFu + ((x >> 16) & 1u);
  return (ushort_t)(x >> 16);
}
__device__ __forceinline__ float fbits(unsigned u) { return __builtin_bit_cast(float, u); }
__device__ __forceinline__ unsigned ubits(float f) { return __builtin_bit_cast(unsigned, f); }

// CDNA packed f32 (VOP3P, double-rate): 2 f32 per instruction.
__device__ __forceinline__ f32x2 pk_add(f32x2 a, f32x2 b) {
  f32x2 d; asm("v_pk_add_f32 %0, %1, %2" : "=v"(d) : "v"(a), "v"(b)); return d;
}
__device__ __forceinline__ f32x2 pk_mul(f32x2 a, f32x2 b) {
  f32x2 d; asm("v_pk_mul_f32 %0, %1, %2" : "=v"(d) : "v"(a), "v"(b)); return d;
}
__device__ __forceinline__ f32x2 pk_fma(f32x2 a, f32x2 b, f32x2 c) {
  f32x2 d; asm("v_pk_fma_f32 %0, %1, %2, %3" : "=v"(d) : "v"(a), "v"(b), "v"(c)); return d;
}

// Raw gfx950 register-pair lane swaps (in-place on both operands).
__device__ __forceinline__ void pl16raw(unsigned &a, unsigned &b) {
  asm("v_permlane16_swap_b32 %0, %1" : "+&v"(a), "+&v"(b));
}
__device__ __forceinline__ void pl32raw(unsigned &a, unsigned &b) {
  asm("v_permlane32_swap_b32 %0, %1" : "+&v"(a), "+&v"(b));
}
template<bool REV> __device__ __forceinline__ void x16(unsigned &a, unsigned &b) {
  if (!REV) pl16raw(a, b); else pl16raw(b, a);
}
template<bool REV> __device__ __forceinline__ void x32(unsigned &a, unsigned &b) {
  if (!REV) pl32raw(a, b); else pl32raw(b, a);
}
// Sum over the 4-lane group {c, c+16, c+32, c+48}; direction-agnostic.
__device__ __forceinline__ float red4(float v) {
  unsigned a = ubits(v), b = a;
  asm("" : "+v"(b));
  pl16raw(a, b);
  float w = fbits(a) + fbits(b);
  unsigned c = ubits(w), d = c;
  asm("" : "+v"(d));
  pl32raw(c, d);
  return fbits(c) + fbits(d);
}

// ---------------- init (fallback only): zero accumulators ----------------
__global__ __launch_bounds__(256) void kinit(float* oacc) {
  int gid = blockIdx.x * 256 + threadIdx.x;
  if (gid < 36864) oacc[gid] = 0.f;   // oacc (32768) + esum (4096), contiguous
}

// ---------------- fused preamble: flag + prep + weff/beff ----------------
__global__ __launch_bounds__(256) void kpre(const float* __restrict__ mem_w,
                                            const float* __restrict__ ln_g,
                                            const float* __restrict__ ln_b,
                                            const float* __restrict__ in_proj_w,
                                            const float* __restrict__ in_proj_b,
                                            const float* __restrict__ Wq, const float* __restrict__ bq,
                                            const float* __restrict__ Wk, const float* __restrict__ bk,
                                            const float* __restrict__ Wv, const float* __restrict__ bv,
                                            short* __restrict__ wbf,
                                            float* __restrict__ avg,
                                            float* __restrict__ weff,
                                            float* __restrict__ beff,
                                            int* __restrict__ flag) {
  int gid = blockIdx.x * 256 + threadIdx.x;
  if (gid < 32768) {
    // mem_w row -> bf16 + row mean
    const float4* src = (const float4*)(mem_w + (size_t)gid * 64);
    int4* dst = (int4*)(wbf + (size_t)gid * 64);
    float sum = 0.f;
#pragma unroll
    for (int c = 0; c < 8; ++c) {
      float4 f0 = src[c * 2], f1 = src[c * 2 + 1];
      sum += f0.x + f0.y + f0.z + f0.w + f1.x + f1.y + f1.z + f1.w;
      int4 pk;
      pk.x = (int)pk2bf(f0.x, f0.y); pk.y = (int)pk2bf(f0.z, f0.w);
      pk.z = (int)pk2bf(f1.x, f1.y); pk.w = (int)pk2bf(f1.z, f1.w);
      dst[c] = pk;
    }
    avg[gid] = sum * 0.015625f;
  } else if (gid < 65536) {
    int j = gid - 32768;
    if (ln_g[j] != 1.0f || ln_b[j] != 0.0f) atomicOr(flag, 1);
  } else if (gid < 77824) {
    int k = gid - 65536;
    int mat = k >> 12, j = (k >> 6) & 63, e = k & 63;
    const float* Wi = in_proj_w + ((size_t)(mat * 64 + j)) * 64;
    const float* Wx = (mat == 0) ? Wq : ((mat == 1) ? Wk : Wv);
    float acc = 0.f;
#pragma unroll 8
    for (int tt = 0; tt < 64; ++tt) acc = fmaf(Wi[tt], Wx[tt * 64 + e], acc);
    weff[k] = acc;
  } else if (gid < 78016) {
    int k = gid - 77824; int mat = k >> 6, j = k & 63;
    const float* Wi = in_proj_w + ((size_t)(mat * 64 + j)) * 64;
    const float* bx = (mat == 0) ? bq : ((mat == 1) ? bk : bv);
    float acc = in_proj_b[mat * 64 + j];
#pragma unroll 8
    for (int tt = 0; tt < 64; ++tt) acc = fmaf(Wi[tt], bx[tt], acc);
    beff[k] = acc;
  }
}

// ---------------- qh = avg_w @ Wq_eff^T + bq_eff, scaled 1/sqrt(DH) --------
__global__ __launch_bounds__(256) void kqh(const float* __restrict__ avg,
                                           const float* __restrict__ weff,
                                           const float* __restrict__ beff,
                                           float* __restrict__ qh) {
  int gid = blockIdx.x * 256 + threadIdx.x;   // 32768 = 512*64
  int m = gid >> 6, j = gid & 63;
  const float* ar = avg + (size_t)m * 64;
  const float* wr = weff + (size_t)j * 64;
  float acc = beff[j];
#pragma unroll 8
  for (int e = 0; e < 64; ++e) acc = fmaf(ar[e], wr[e], acc);
  qh[gid] = acc * 0.35355339059327373f;
}

// ---------------- the sequential memory scan (register-resident h) --------
// 256 thr (4 waves), 64 rows/block, 512 blocks -> 2 independent blocks/CU.
// h stays in registers; C-frag -> next B-frag via cvt_pk + permlane swaps.
// LN math uses packed-f32 VOP3P. LDS = W ring only (4 bufs).
#define KSTEP(PP, WFC, WFN, GCa, GCb, GNa, GNb)                                \
  {                                                                            \
    const int m = mb + PP;                                                     \
    if (m + 3 < 512) {                                                         \
      GNa = wp[(m + 3) * 512 + t];                                             \
      GNb = wp[(m + 3) * 512 + t + 256];                                       \
    }                                                                          \
    if (m + 1 < 512) {                                                         \
      const char* rb = (const char*)wlds[(PP + 1) & 3];                        \
      _Pragma("unroll")                                                        \
      for (int i = 0; i < 8; ++i) WFN[i] = *(const short8*)(rb + wrd[i]);      \
    }                                                                          \
    f32x4 acc0 = __builtin_amdgcn_mfma_f32_16x16x32_bf16(WFC[0], hf0, z4, 0, 0, 0); \
    f32x4 acc1 = __builtin_amdgcn_mfma_f32_16x16x32_bf16(WFC[2], hf0, z4, 0, 0, 0); \
    f32x4 acc2 = __builtin_amdgcn_mfma_f32_16x16x32_bf16(WFC[4], hf0, z4, 0, 0, 0); \
    f32x4 acc3 = __builtin_amdgcn_mfma_f32_16x16x32_bf16(WFC[6], hf0, z4, 0, 0, 0); \
    acc0 = __builtin_amdgcn_mfma_f32_16x16x32_bf16(WFC[1], hf1, acc0, 0, 0, 0); \
    acc1 = __builtin_amdgcn_mfma_f32_16x16x32_bf16(WFC[3], hf1, acc1, 0, 0, 0); \
    acc2 = __builtin_amdgcn_mfma_f32_16x16x32_bf16(WFC[5], hf1, acc2, 0, 0, 0); \
    acc3 = __builtin_amdgcn_mfma_f32_16x16x32_bf16(WFC[7], hf1, acc3, 0, 0, 0); \
    yp[0] = (f32x2){fmaxf(acc0[0], 0.f), fmaxf(acc0[1], 0.f)};                 \
    yp[1] = (f32x2){fmaxf(acc0[2], 0.f), fmaxf(acc0[3], 0.f)};                 \
    yp[2] = (f32x2){fmaxf(acc1[0], 0.f), fmaxf(acc1[1], 0.f)};                 \
    yp[3] = (f32x2){fmaxf(acc1[2], 0.f), fmaxf(acc1[3], 0.f)};                 \
    yp[4] = (f32x2){fmaxf(acc2[0], 0.f), fmaxf(acc2[1], 0.f)};                 \
    yp[5] = (f32x2){fmaxf(acc2[2], 0.f), fmaxf(acc2[3], 0.f)};                 \
    yp[6] = (f32x2){fmaxf(acc3[0], 0.f), fmaxf(acc3[1], 0.f)};                 \
    yp[7] = (f32x2){fmaxf(acc3[2], 0.f), fmaxf(acc3[3], 0.f)};                 \
    f32x2 sp = pk_add(yp[0], yp[1]);                                           \
    f32x2 qp = pk_mul(yp[0], yp[0]);                                           \
    qp = pk_fma(yp[1], yp[1], qp);                                             \
    _Pragma("unroll")                                                          \
    for (int i = 2; i < 8; ++i) {                                              \
      sp = pk_add(sp, yp[i]);                                                  \
      qp = pk_fma(yp[i], yp[i], qp);                                           \
    }                                                                          \
    float s = red4(sp[0] + sp[1]);                                             \
    float sq = red4(qp[0] + qp[1]);                                            \
    const float mean = s * 0.015625f;                                          \
    const float var = fmaf(sq, 0.015625f, -mean * mean);                       \
    const float rs = rsqrtf(var + 1e-5f);                                      \
    const float cc = -mean * rs;                                               \
    if (gb) {                                                                  \
      _Pragma("unroll")                                                        \
      for (int mt = 0; mt < 4; ++mt) {                                         \
        float4 gg = *(const float4*)(ln_g + m * 64 + mt * 16 + lg * 4);        \
        float4 bb = *(const float4*)(ln_b + m * 64 + mt * 16 + lg * 4);        \
        yp[mt * 2][0]     = fmaf(fmaf(yp[mt * 2][0], rs, cc), gg.x, bb.x);     \
        yp[mt * 2][1]     = fmaf(fmaf(yp[mt * 2][1], rs, cc), gg.y, bb.y);     \
        yp[mt * 2 + 1][0] = fmaf(fmaf(yp[mt * 2 + 1][0], rs, cc), gg.z, bb.z); \
        yp[mt * 2 + 1][1] = fmaf(fmaf(yp[mt * 2 + 1][1], rs, cc), gg.w, bb.w); \
      }                                                                        \
    } else {                                                                   \
      const f32x2 rs2 = (f32x2){rs, rs};                                       \
      const f32x2 cc2 = (f32x2){cc, cc};                                       \
      _Pragma("unroll")                                                        \
      for (int i = 0; i < 8; ++i) yp[i] = pk_fma(yp[i], rs2, cc2);             \
    }                                                                          \
    if (m < 511) {                                                             \
      unsigned Q0 = pk2bf(yp[0][0], yp[0][1]), Q1 = pk2bf(yp[1][0], yp[1][1]); \
      unsigned Q2 = pk2bf(yp[2][0], yp[2][1]), Q3 = pk2bf(yp[3][0], yp[3][1]); \
      unsigned Q4 = pk2bf(yp[4][0], yp[4][1]), Q5 = pk2bf(yp[5][0], yp[5][1]); \
      unsigned Q6 = pk2bf(yp[6][0], yp[6][1]), Q7 = pk2bf(yp[7][0], yp[7][1]); \
      x32<R32>(Q0, Q2); x16<R16>(Q0, Q2);                                      \
      x32<R32>(Q1, Q3); x16<R16>(Q1, Q3);                                      \
      x32<R32>(Q4, Q6); x16<R16>(Q4, Q6);                                      \
      x32<R32>(Q5, Q7); x16<R16>(Q5, Q7);                                      \
      union { unsigned d[4]; short8 s8; } uu0, uu1;                            \
      uu0.d[0] = Q0; uu0.d[1] = Q1; uu0.d[2] = Q2; uu0.d[3] = Q3;              \
      uu1.d[0] = Q4; uu1.d[1] = Q5; uu1.d[2] = Q6; uu1.d[3] = Q7;              \
      hf0 = uu0.s8; hf1 = uu1.s8;                                              \
    }                                                                          \
    if (m + 2 < 512) {                                                         \
      char* wbw = (char*)wlds[(PP + 2) & 3];                                   \
      *(int4*)(wbw + so0) = GCa;                                               \
      *(int4*)(wbw + so0 + 4096) = GCb;                                        \
    }                                                                          \
    asm volatile("s_waitcnt lgkmcnt(0)" ::: "memory");                         \
    __builtin_amdgcn_s_barrier();                                              \
  }

template<bool R16, bool R32>
__device__ void kscan_body(const float* __restrict__ x,
                           const short* __restrict__ wbf,
                           const float* __restrict__ ln_g,
                           const float* __restrict__ ln_b,
                           int gb, float* __restrict__ mem_out,
                           short* __restrict__ wldsb) {
  short (*wlds)[64 * 64] = (short (*)[64 * 64])wldsb;
  const int t = threadIdx.x;
  const int lane = t & 63;
  const int wv = t >> 6;                 // 0..3
  const int lcol = lane & 15;
  const int lg = lane >> 4;
  const int blk = blockIdx.x;
  const int r = wv * 16 + lcol;          // this lane's h row (0..63)

  const int wsw = (lcol & 7) << 4;
  int wrd[8];                            // A-frag offsets [mt][khalf]
#pragma unroll
  for (int mt = 0; mt < 4; ++mt) {
    wrd[mt * 2]     = mt * 2048 + lcol * 128 + ((lg * 16) ^ wsw);
    wrd[mt * 2 + 1] = mt * 2048 + lcol * 128 + ((lg * 16 + 64) ^ wsw);
  }
  const int so0 = (t * 16) ^ ((((t * 16) >> 7) & 7) << 4);
  const int4* wp = (const int4*)wbf;

  // initial h B-fragments straight from x
  short8 hf0, hf1;
  {
    const float4* xr = (const float4*)(x + ((size_t)(blk * 64 + r)) * 64);
    float4 a0 = xr[lg * 2], a1 = xr[lg * 2 + 1];
    float4 b0 = xr[8 + lg * 2], b1 = xr[8 + lg * 2 + 1];
    union { unsigned d[4]; short8 s8; } u0, u1;
    u0.d[0] = pk2bf(a0.x, a0.y); u0.d[1] = pk2bf(a0.z, a0.w);
    u0.d[2] = pk2bf(a1.x, a1.y); u0.d[3] = pk2bf(a1.z, a1.w);
    u1.d[0] = pk2bf(b0.x, b0.y); u1.d[1] = pk2bf(b0.z, b0.w);
    u1.d[2] = pk2bf(b1.x, b1.y); u1.d[3] = pk2bf(b1.z, b1.w);
    hf0 = u0.s8; hf1 = u1.s8;
  }
  // stage W[0] -> buf0, W[1] -> buf1; preload W[2] into registers
  {
    *(int4*)((char*)wlds[0] + so0) = wp[t];
    *(int4*)((char*)wlds[0] + so0 + 4096) = wp[t + 256];
    *(int4*)((char*)wlds[1] + so0) = wp[512 + t];
    *(int4*)((char*)wlds[1] + so0 + 4096) = wp[512 + t + 256];
  }
  int4 g0a = wp[1024 + t], g0b = wp[1024 + t + 256];
  int4 g1a, g1b;
  __syncthreads();

  short8 wfA[8], wfB[8];
#pragma unroll
  for (int i = 0; i < 8; ++i) wfA[i] = *(const short8*)((const char*)wlds[0] + wrd[i]);

  const f32x4 z4 = {0.f, 0.f, 0.f, 0.f};
  f32x2 yp[8];

  for (int mb = 0; mb < 512; mb += 4) {
    KSTEP(0, wfA, wfB, g0a, g0b, g1a, g1b)
    KSTEP(1, wfB, wfA, g1a, g1b, g0a, g0b)
    KSTEP(2, wfA, wfB, g0a, g0b, g1a, g1b)
    KSTEP(3, wfB, wfA, g1a, g1b, g0a, g0b)
  }

  // epilogue: yp holds the final LN output (f32) for row r
  float* mo = mem_out + ((size_t)(blk * 64 + r)) * 64;
#pragma unroll
  for (int mt = 0; mt < 4; ++mt)
    *(float4*)(mo + mt * 16 + lg * 4) =
        make_float4(yp[mt * 2][0], yp[mt * 2][1], yp[mt * 2 + 1][0], yp[mt * 2 + 1][1]);
}

__global__ __launch_bounds__(256, 2) void kscan(
    const float* __restrict__ x, const short* __restrict__ wbf,
    const float* __restrict__ ln_g, const float* __restrict__ ln_b,
    const int* __restrict__ flagp, float* __restrict__ mem_out) {
  __shared__ short wlds[4][64 * 64];     // W ring, bf16, XOR-swizzled, 32 KiB
  const int lane = threadIdx.x & 63;
  const int gb = *flagp;
  // Probe the HW direction of permlane{16,32}_swap (uniform, deterministic).
  unsigned pa = (unsigned)lane, pb = 1000u + (unsigned)lane;
  pl16raw(pa, pb);
  const bool r16 = (__builtin_amdgcn_readfirstlane((int)pa) != 0);
  unsigned qa = (unsigned)lane, qb = 2000u + (unsigned)lane;
  pl32raw(qa, qb);
  const bool r32 = (__builtin_amdgcn_readfirstlane((int)qa) != 0);
  if (!r16) {
    if (!r32) kscan_body<false, false>(x, wbf, ln_g, ln_b, gb, mem_out, &wlds[0][0]);
    else      kscan_body<false, true >(x, wbf, ln_g, ln_b, gb, mem_out, &wlds[0][0]);
  } else {
    if (!r32) kscan_body<true, false >(x, wbf, ln_g, ln_b, gb, mem_out, &wlds[0][0]);
    else      kscan_body<true, true  >(x, wbf, ln_g, ln_b, gb, mem_out, &wlds[0][0]);
  }
}

// ---------------- kh/vh = mem_out @ W{k,v}_eff^T + b, stored bf16 ----------
__global__ __launch_bounds__(256) void kkv(const float* __restrict__ mem_out,
                                           const float* __restrict__ weff,
                                           const float* __restrict__ beff,
                                           short* __restrict__ khvh) {
  __shared__ short kvs[128 * 128];
  const int t = threadIdx.x;
  const int nl = t >> 1;
  const int jh = (t & 1) * 32;
  const int n = blockIdx.x * 128 + nl;
  float mo[64];
  const float4* mop = (const float4*)(mem_out + (size_t)n * 64);
#pragma unroll
  for (int c = 0; c < 16; ++c) {
    float4 f = mop[c];
    mo[c * 4] = f.x; mo[c * 4 + 1] = f.y; mo[c * 4 + 2] = f.z; mo[c * 4 + 3] = f.w;
  }
  const float* wk = weff + 4096;
  const float* wvp = weff + 8192;
  const float* bk = beff + 64;
  const float* bv = beff + 128;
  for (int jj = 0; jj < 32; ++jj) {
    const int j = jh + jj;
    float ak = bk[j], av = bv[j];
    const float* wkr = wk + (size_t)j * 64;
    const float* wvr = wvp + (size_t)j * 64;
#pragma unroll 8
    for (int e = 0; e < 64; ++e) { ak = fmaf(mo[e], wkr[e], ak); av = fmaf(mo[e], wvr[e], av); }
    kvs[nl * 128 + j] = (short)f2bf1(ak);
    kvs[nl * 128 + 64 + j] = (short)f2bf1(av);
  }
  __syncthreads();
  int4* dst = (int4*)(khvh + (size_t)blockIdx.x * 16384);
  const int4* srcl = (const int4*)kvs;
#pragma unroll
  for (int c = 0; c < 8; ++c) dst[t + c * 256] = srcl[t + c * 256];
}

// ---------------- attention, atomic-free two-stage (f32 LDS tiles) --------
__global__ __launch_bounds__(512) void kattn2(const short* __restrict__ khvh,
                                              const float* __restrict__ qh,
                                              float* __restrict__ pO,
                                              float* __restrict__ pE) {
  __shared__ float kvf[64 * 128];   // 64-key tile, f32 (K|V), 32 KiB
  const int t = threadIdx.x;
  const int hh = t >> 6;
  const int ml = t & 63;
  const int c = blockIdx.x >> 2;
  const int mc = blockIdx.x & 3;
  const int m0 = mc * 128 + ml;
  const int m1 = m0 + 64;
  float q0[8], q1[8], o0[8], o1[8];
  float e0 = 0.f, e1 = 0.f;
  {
    const float4* qp0 = (const float4*)(qh + (size_t)m0 * 64 + hh * 8);
    const float4* qp1 = (const float4*)(qh + (size_t)m1 * 64 + hh * 8);
    float4 a = qp0[0], b = qp0[1], cc2 = qp1[0], d2 = qp1[1];
    q0[0]=a.x; q0[1]=a.y; q0[2]=a.z; q0[3]=a.w; q0[4]=b.x; q0[5]=b.y; q0[6]=b.z; q0[7]=b.w;
    q1[0]=cc2.x; q1[1]=cc2.y; q1[2]=cc2.z; q1[3]=cc2.w; q1[4]=d2.x; q1[5]=d2.y; q1[6]=d2.z; q1[7]=d2.w;
#pragma unroll
    for (int d = 0; d < 8; ++d) { o0[d] = 0.f; o1[d] = 0.f; }
  }
  for (int tile = 0; tile < 8; ++tile) {
    if (tile) __syncthreads();
    const int4* src = (const int4*)(khvh + ((size_t)(c * 512 + tile * 64)) * 128);
#pragma unroll
    for (int u = 0; u < 2; ++u) {
      int4 rawv = src[t + u * 512];
      float* dp = kvf + ((size_t)(t + u * 512)) * 8;
      unsigned w0 = (unsigned)rawv.x, w1 = (unsigned)rawv.y;
      unsigned w2 = (unsigned)rawv.z, w3 = (unsigned)rawv.w;
      float4 f0, f1;
      f0.x = bf2f((ushort_t)(w0 & 0xffffu)); f0.y = bf2f((ushort_t)(w0 >> 16));
      f0.z = bf2f((ushort_t)(w1 & 0xffffu)); f0.w = bf2f((ushort_t)(w1 >> 16));
      f1.x = bf2f((ushort_t)(w2 & 0xffffu)); f1.y = bf2f((ushort_t)(w2 >> 16));
      f1.z = bf2f((ushort_t)(w3 & 0xffffu)); f1.w = bf2f((ushort_t)(w3 >> 16));
      *(float4*)dp = f0; *(float4*)(dp + 4) = f1;
    }
    __syncthreads();
    for (int n = 0; n < 64; ++n) {
      const float4 ka = *(const float4*)(kvf + n * 128 + hh * 8);
      const float4 kb = *(const float4*)(kvf + n * 128 + hh * 8 + 4);
      const float4 va = *(const float4*)(kvf + n * 128 + 64 + hh * 8);
      const float4 vb = *(const float4*)(kvf + n * 128 + 64 + hh * 8 + 4);
      float s0 = 0.f, s1 = 0.f;
      s0 = fmaf(q0[0], ka.x, s0); s0 = fmaf(q0[1], ka.y, s0);
      s0 = fmaf(q0[2], ka.z, s0); s0 = fmaf(q0[3], ka.w, s0);
      s0 = fmaf(q0[4], kb.x, s0); s0 = fmaf(q0[5], kb.y, s0);
      s0 = fmaf(q0[6], kb.z, s0); s0 = fmaf(q0[7], kb.w, s0);
      s1 = fmaf(q1[0], ka.x, s1); s1 = fmaf(q1[1], ka.y, s1);
      s1 = fmaf(q1[2], ka.z, s1); s1 = fmaf(q1[3], ka.w, s1);
      s1 = fmaf(q1[4], kb.x, s1); s1 = fmaf(q1[5], kb.y, s1);
      s1 = fmaf(q1[6], kb.z, s1); s1 = fmaf(q1[7], kb.w, s1);
      float p0 = __expf(s0), p1 = __expf(s1);
      e0 += p0; e1 += p1;
      o0[0] = fmaf(p0, va.x, o0[0]); o0[1] = fmaf(p0, va.y, o0[1]);
      o0[2] = fmaf(p0, va.z, o0[2]); o0[3] = fmaf(p0, va.w, o0[3]);
      o0[4] = fmaf(p0, vb.x, o0[4]); o0[5] = fmaf(p0, vb.y, o0[5]);
      o0[6] = fmaf(p0, vb.z, o0[6]); o0[7] = fmaf(p0, vb.w, o0[7]);
      o1[0] = fmaf(p1, va.x, o1[0]); o1[1] = fmaf(p1, va.y, o1[1]);
      o1[2] = fmaf(p1, va.z, o1[2]); o1[3] = fmaf(p1, va.w, o1[3]);
      o1[4] = fmaf(p1, vb.x, o1[4]); o1[5] = fmaf(p1, vb.y, o1[5]);
      o1[6] = fmaf(p1, vb.z, o1[6]); o1[7] = fmaf(p1, vb.w, o1[7]);
    }
  }
  const int idx0 = hh * 512 + m0;
  const int idx1 = hh * 512 + m1;
  pE[(size_t)c * 4096 + idx0] = e0;
  pE[(size_t)c * 4096 + idx1] = e1;
  float4* po0 = (float4*)(pO + (size_t)c * 32768 + (size_t)idx0 * 8);
  float4* po1 = (float4*)(pO + (size_t)c * 32768 + (size_t)idx1 * 8);
  po0[0] = make_float4(o0[0], o0[1], o0[2], o0[3]);
  po0[1] = make_float4(o0[4], o0[5], o0[6], o0[7]);
  po1[0] = make_float4(o1[0], o1[1], o1[2], o1[3]);
  po1[1] = make_float4(o1[4], o1[5], o1[6], o1[7]);
}

// ---------------- reduce partials -> oacc / esum ----------------
__global__ __launch_bounds__(256) void kred(const float* __restrict__ pO,
                                            const float* __restrict__ pE,
                                            float* __restrict__ oacc,
                                            float* __restrict__ esum) {
  int gid = blockIdx.x * 256 + threadIdx.x;
  if (gid < 32768) {
    float s = 0.f;
#pragma unroll 8
    for (int ci = 0; ci < NCH; ++ci) s += pO[(size_t)ci * 32768 + gid];
    oacc[gid] = s;
  } else if (gid < 36864) {
    int j = gid - 32768;
    float s = 0.f;
#pragma unroll 8
    for (int ci = 0; ci < NCH; ++ci) s += pE[(size_t)ci * 4096 + j];
    esum[j] = s;
  }
}

// ---------------- attention fallback (atomics) if ws too small ----------
__global__ __launch_bounds__(512) void kattn_atomic(const short* __restrict__ khvh,
                                                    const float* __restrict__ qh,
                                                    float* __restrict__ oacc,
                                                    float* __restrict__ esum) {
  __shared__ short kv[128 * 128];
  const int t = threadIdx.x;
  const int hh = t >> 6;
  const int ms = t & 63;
  {
    const int4* src = (const int4*)(khvh + (size_t)blockIdx.x * 16384);
    int4* d = (int4*)kv;
#pragma unroll
    for (int c = 0; c < 4; ++c) d[t + c * 512] = src[t + c * 512];
  }
  __syncthreads();
  float q[8][8], o[8][8], es[8];
#pragma unroll
  for (int i = 0; i < 8; ++i) {
    const float4* qp = (const float4*)(qh + ((size_t)(ms + i * 64)) * 64 + hh * 8);
    float4 q0 = qp[0], q1 = qp[1];
    q[i][0] = q0.x; q[i][1] = q0.y; q[i][2] = q0.z; q[i][3] = q0.w;
    q[i][4] = q1.x; q[i][5] = q1.y; q[i][6] = q1.z; q[i][7] = q1.w;
    es[i] = 0.f;
#pragma unroll
    for (int d = 0; d < 8; ++d) o[i][d] = 0.f;
  }
  for (int n = 0; n < 128; ++n) {
    const short8 kraw = *(const short8*)(kv + n * 128 + hh * 8);
    const short8 vraw = *(const short8*)(kv + n * 128 + 64 + hh * 8);
    float kf[8], vf[8];
#pragma unroll
    for (int d = 0; d < 8; ++d) {
      kf[d] = bf2f((ushort_t)kraw[d]);
      vf[d] = bf2f((ushort_t)vraw[d]);
    }
#pragma unroll
    for (int i = 0; i < 8; ++i) {
      float s = 0.f;
#pragma unroll
      for (int d = 0; d < 8; ++d) s = fmaf(q[i][d], kf[d], s);
      float p = __expf(s);
      es[i] += p;
#pragma unroll
      for (int d = 0; d < 8; ++d) o[i][d] = fmaf(p, vf[d], o[i][d]);
    }
  }
#pragma unroll
  for (int i = 0; i < 8; ++i) {
    const int m = ms + i * 64;
    atomicAdd(&esum[hh * 512 + m], es[i]);
#pragma unroll
    for (int d = 0; d < 8; ++d) atomicAdd(&oacc[((size_t)(hh * 512 + m)) * 8 + d], o[i][d]);
  }
}

// ---------------- attn_out + ratio ----------------
__global__ __launch_bounds__(256) void kratio(const float* __restrict__ oacc,
                                              const float* __restrict__ esum,
                                              const float* __restrict__ out_w,
                                              const float* __restrict__ out_b,
                                              const float* __restrict__ avg,
                                              float* __restrict__ ratio) {
  int gid = blockIdx.x * 256 + threadIdx.x;  // 32768 = 512*64
  int m = gid >> 6, e = gid & 63;
  float of[64];
#pragma unroll
  for (int h = 0; h < 8; ++h) {
    float inv = 1.f / esum[h * 512 + m];
    const float* op = oacc + ((size_t)(h * 512 + m)) * 8;
#pragma unroll
    for (int d = 0; d < 8; ++d) of[h * 8 + d] = op[d] * inv;
  }
  float a = out_b[e];
  const float* wr = out_w + (size_t)e * 64;
#pragma unroll 8
  for (int j = 0; j < 64; ++j) a = fmaf(of[j], wr[j], a);
  ratio[gid] = 1.f + a / avg[gid];
}

// ---------------- new_mem_w = mem_w * ratio ----------------
__global__ __launch_bounds__(256) void kfinal(const float* __restrict__ mem_w,
                                              const float* __restrict__ ratio,
                                              float* __restrict__ out1) {
  int gid = blockIdx.x * 256 + threadIdx.x;  // 524288 float4s
  float rr = ratio[gid >> 4];
  float4 w = ((const float4*)mem_w)[gid];
  float4 o; o.x = w.x * rr; o.y = w.y * rr; o.z = w.z * rr; o.w = w.w * rr;
  ((float4*)out1)[gid] = o;
}

extern "C" void kernel_launch(void* const* d_in, const int* in_sizes, int n_in,
                              void* d_out, int out_size, void* d_ws, size_t ws_size,
                              hipStream_t stream) {
  (void)in_sizes; (void)n_in; (void)out_size;
  const float* x         = (const float*)d_in[0];
  const float* mem_w     = (const float*)d_in[1];
  const float* ln_g      = (const float*)d_in[2];
  const float* ln_b      = (const float*)d_in[3];
  const float* Wq        = (const float*)d_in[4];
  const float* bq        = (const float*)d_in[5];
  const float* Wk        = (const float*)d_in[6];
  const float* bk        = (const float*)d_in[7];
  const float* Wv        = (const float*)d_in[8];
  const float* bv        = (const float*)d_in[9];
  const float* in_proj_w = (const float*)d_in[10];
  const float* in_proj_b = (const float*)d_in[11];
  const float* out_w     = (const float*)d_in[12];
  const float* out_b     = (const float*)d_in[13];

  float* dout = (float*)d_out;
  char* ws = (char*)d_ws;
  short* wbf   = (short*)(ws + WBF_OFF);
  short* khvh  = (short*)(ws + KVH_OFF);
  float* qh    = (float*)(ws + QH_OFF);
  float* avg   = (float*)(ws + AVG_OFF);
  float* weff  = (float*)(ws + WEFF_OFF);
  float* beff  = (float*)(ws + BEFF_OFF);
  float* oacc  = (float*)(ws + OACC_OFF);
  float* esum  = (float*)(ws + ESUM_OFF);
  float* ratio = (float*)(ws + RATIO_OFF);
  int*   flag  = (int*)(ws + FLAG_OFF);
  float* pO    = (float*)(ws + PO_OFF);
  float* pE    = (float*)(ws + PE_OFF);

  float* mem_out = dout;              // output 0: (32768, 64)
  float* out1    = dout + 2097152;    // output 1: (512, 64, 64)

  const bool use_part = (ws_size >= WS_NEED);   // host-constant: graph-safe

  hipMemsetAsync(flag, 0, 4, stream);
  kpre<<<305, 256, 0, stream>>>(mem_w, ln_g, ln_b, in_proj_w, in_proj_b,
                                Wq, bq, Wk, bk, Wv, bv, wbf, avg, weff, beff, flag);
  kqh<<<128, 256, 0, stream>>>(avg, weff, beff, qh);
  kscan<<<512, 256, 0, stream>>>(x, wbf, ln_g, ln_b, flag, mem_out);
  kkv<<<256, 256, 0, stream>>>(mem_out, weff, beff, khvh);
  if (use_part) {
    kattn2<<<NCH * 4, 512, 0, stream>>>(khvh, qh, pO, pE);
    kred<<<144, 256, 0, stream>>>(pO, pE, oacc, esum);
  } else {
    kinit<<<144, 256, 0, stream>>>(oacc);
    kattn_atomic<<<256, 512, 0, stream>>>(khvh, qh, oacc, esum);
  }
  kratio<<<128, 256, 0, stream>>>(oacc, esum, out_w, out_b, avg, ratio);
  kfinal<<<2048, 256, 0, stream>>>(mem_w, ratio, out1);
}

// Round 7
// 614.923 us; speedup vs baseline: 1.0217x; 1.0217x over previous
//
#include <hip/hip_runtime.h>
#include <hip/hip_bf16.h>
#include <cstdint>
#include <cstddef>

typedef __attribute__((ext_vector_type(8))) short short8;
typedef __attribute__((ext_vector_type(4))) float f32x4;
typedef unsigned short ushort_t;

// ---------------- ws layout (bytes) ----------------
#define WBF_OFF   0u            // 512*64*64 bf16 (linear) = 4 MiB
#define KVH_OFF   4194304u      // 32768*128 bf16 (kh|vh per row) = 8 MiB
#define QH_OFF    12582912u     // 512*64 f32 (pre-scaled by 1/sqrt(8))
#define AVG_OFF   12713984u     // 512*64 f32 row means of mem_w
#define WEFF_OFF  12845056u     // 3 * 64*64 f32 combined projections
#define BEFF_OFF  12894208u     // 3 * 64 f32 combined biases
#define OACC_OFF  12894976u     // 8*512*8 f32 attention numerator
#define ESUM_OFF  13026048u     // 8*512 f32 softmax denominator
#define FLAG_OFF  13173504u     // int: nontrivial ln_g/ln_b flag
#define PO_OFF    13180928u     // 64 chunks * 32768 f32 partial O = 8 MiB
#define PE_OFF    21569536u     // 64 chunks * 4096 f32 partial esum = 1 MiB
#define WS_NEED   22618112ull   // bytes required for the partial scheme
#define NCH 64                  // key chunks (512 keys each)

__device__ __forceinline__ float bf2f(ushort_t u) {
  union { unsigned int i; float f; } c; c.i = ((unsigned int)u) << 16; return c.f;
}
__device__ __forceinline__ unsigned pk2bf(float a, float b) {
  __hip_bfloat162 h = __float22bfloat162_rn(make_float2(a, b));
  unsigned u;
  __builtin_memcpy(&u, &h, 4);
  return u;
}
__device__ __forceinline__ ushort_t f2bf1(float f) {
  union { float f; unsigned int i; } c; c.f = f;
  unsigned int x = c.i;
  x += 0x7FFFu + ((x >> 16) & 1u);
  return (ushort_t)(x >> 16);
}
__device__ __forceinline__ float fbits(unsigned u) { return __builtin_bit_cast(float, u); }
__device__ __forceinline__ unsigned ubits(float f) { return __builtin_bit_cast(unsigned, f); }

// Raw gfx950 register-pair lane swaps (in-place on both operands).
// Tied "+v" (no early-clobber): a,b hold distinct values at every call site.
__device__ __forceinline__ void pl16raw(unsigned &a, unsigned &b) {
  asm("v_permlane16_swap_b32 %0, %1" : "+v"(a), "+v"(b));
}
__device__ __forceinline__ void pl32raw(unsigned &a, unsigned &b) {
  asm("v_permlane32_swap_b32 %0, %1" : "+v"(a), "+v"(b));
}
// red4 needs distinct registers even though values are equal: early-clobber copies.
__device__ __forceinline__ void pl16raw_ec(unsigned &a, unsigned &b) {
  asm("v_permlane16_swap_b32 %0, %1" : "+&v"(a), "+&v"(b));
}
__device__ __forceinline__ void pl32raw_ec(unsigned &a, unsigned &b) {
  asm("v_permlane32_swap_b32 %0, %1" : "+&v"(a), "+&v"(b));
}
template<bool REV> __device__ __forceinline__ void x16(unsigned &a, unsigned &b) {
  if (!REV) pl16raw(a, b); else pl16raw(b, a);
}
template<bool REV> __device__ __forceinline__ void x32(unsigned &a, unsigned &b) {
  if (!REV) pl32raw(a, b); else pl32raw(b, a);
}
// Sum over the 4-lane group {c, c+16, c+32, c+48}; direction-agnostic.
__device__ __forceinline__ float red4(float v) {
  unsigned a = ubits(v), b = a;
  asm("" : "+v"(b));
  pl16raw_ec(a, b);
  float w = fbits(a) + fbits(b);
  unsigned c = ubits(w), d = c;
  asm("" : "+v"(d));
  pl32raw_ec(c, d);
  return fbits(c) + fbits(d);
}

// ---------------- init (fallback only): zero accumulators ----------------
__global__ __launch_bounds__(256) void kinit(float* oacc) {
  int gid = blockIdx.x * 256 + threadIdx.x;
  if (gid < 36864) oacc[gid] = 0.f;   // oacc (32768) + esum (4096), contiguous
}

// ---------------- fused preamble: flag + prep + weff/beff ----------------
__global__ __launch_bounds__(256) void kpre(const float* __restrict__ mem_w,
                                            const float* __restrict__ ln_g,
                                            const float* __restrict__ ln_b,
                                            const float* __restrict__ in_proj_w,
                                            const float* __restrict__ in_proj_b,
                                            const float* __restrict__ Wq, const float* __restrict__ bq,
                                            const float* __restrict__ Wk, const float* __restrict__ bk,
                                            const float* __restrict__ Wv, const float* __restrict__ bv,
                                            short* __restrict__ wbf,
                                            float* __restrict__ avg,
                                            float* __restrict__ weff,
                                            float* __restrict__ beff,
                                            int* __restrict__ flag) {
  int gid = blockIdx.x * 256 + threadIdx.x;
  if (gid < 32768) {
    const float4* src = (const float4*)(mem_w + (size_t)gid * 64);
    int4* dst = (int4*)(wbf + (size_t)gid * 64);
    float sum = 0.f;
#pragma unroll
    for (int c = 0; c < 8; ++c) {
      float4 f0 = src[c * 2], f1 = src[c * 2 + 1];
      sum += f0.x + f0.y + f0.z + f0.w + f1.x + f1.y + f1.z + f1.w;
      int4 pk;
      pk.x = (int)pk2bf(f0.x, f0.y); pk.y = (int)pk2bf(f0.z, f0.w);
      pk.z = (int)pk2bf(f1.x, f1.y); pk.w = (int)pk2bf(f1.z, f1.w);
      dst[c] = pk;
    }
    avg[gid] = sum * 0.015625f;
  } else if (gid < 65536) {
    int j = gid - 32768;
    if (ln_g[j] != 1.0f || ln_b[j] != 0.0f) atomicOr(flag, 1);
  } else if (gid < 77824) {
    int k = gid - 65536;
    int mat = k >> 12, j = (k >> 6) & 63, e = k & 63;
    const float* Wi = in_proj_w + ((size_t)(mat * 64 + j)) * 64;
    const float* Wx = (mat == 0) ? Wq : ((mat == 1) ? Wk : Wv);
    float acc = 0.f;
#pragma unroll 8
    for (int tt = 0; tt < 64; ++tt) acc = fmaf(Wi[tt], Wx[tt * 64 + e], acc);
    weff[k] = acc;
  } else if (gid < 78016) {
    int k = gid - 77824; int mat = k >> 6, j = k & 63;
    const float* Wi = in_proj_w + ((size_t)(mat * 64 + j)) * 64;
    const float* bx = (mat == 0) ? bq : ((mat == 1) ? bk : bv);
    float acc = in_proj_b[mat * 64 + j];
#pragma unroll 8
    for (int tt = 0; tt < 64; ++tt) acc = fmaf(Wi[tt], bx[tt], acc);
    beff[k] = acc;
  }
}

// ---------------- qh = avg_w @ Wq_eff^T + bq_eff, scaled 1/sqrt(DH) --------
__global__ __launch_bounds__(256) void kqh(const float* __restrict__ avg,
                                           const float* __restrict__ weff,
                                           const float* __restrict__ beff,
                                           float* __restrict__ qh) {
  int gid = blockIdx.x * 256 + threadIdx.x;   // 32768 = 512*64
  int m = gid >> 6, j = gid & 63;
  const float* ar = avg + (size_t)m * 64;
  const float* wr = weff + (size_t)j * 64;
  float acc = beff[j];
#pragma unroll 8
  for (int e = 0; e < 64; ++e) acc = fmaf(ar[e], wr[e], acc);
  qh[gid] = acc * 0.35355339059327373f;
}

// ---------------- the sequential memory scan (register-resident h) --------
// 512 thr (8 waves), 128 rows/block, 256 blocks (1/CU). h in registers;
// C-frag -> next B-frag via cvt_pk + permlane swaps. W in an 8-slot LDS ring
// (64 KiB); barrier every 4 steps (reads/writes disjoint within a superstep).
// Step PP (mod 8): reads frag slot (PP+1)&7, writes W[mb+5+PP] to slot
// (5+PP)&7, issues global load of W[mb+9+PP].
#define KS(PP, WFC, WFN, GW, GL, BAR)                                          \
  {                                                                            \
    const int m = mb + PP;                                                     \
    if (mb + 9 + PP < 512) GL = wp[(size_t)(mb + 9 + PP) * 512 + t];           \
    if (mb + 5 + PP < 512)                                                     \
      *(int4*)(wldsc + (((5 + PP) & 7) * 8192) + so0) = GW;                    \
    if (m + 1 < 512) {                                                         \
      const char* rb = wldsc + (((PP + 1) & 7) * 8192);                        \
      _Pragma("unroll")                                                        \
      for (int i = 0; i < 8; ++i) WFN[i] = *(const short8*)(rb + wrd[i]);      \
    }                                                                          \
    f32x4 acc0 = __builtin_amdgcn_mfma_f32_16x16x32_bf16(WFC[0], hf0, z4, 0, 0, 0); \
    f32x4 acc1 = __builtin_amdgcn_mfma_f32_16x16x32_bf16(WFC[2], hf0, z4, 0, 0, 0); \
    f32x4 acc2 = __builtin_amdgcn_mfma_f32_16x16x32_bf16(WFC[4], hf0, z4, 0, 0, 0); \
    f32x4 acc3 = __builtin_amdgcn_mfma_f32_16x16x32_bf16(WFC[6], hf0, z4, 0, 0, 0); \
    acc0 = __builtin_amdgcn_mfma_f32_16x16x32_bf16(WFC[1], hf1, acc0, 0, 0, 0); \
    acc1 = __builtin_amdgcn_mfma_f32_16x16x32_bf16(WFC[3], hf1, acc1, 0, 0, 0); \
    acc2 = __builtin_amdgcn_mfma_f32_16x16x32_bf16(WFC[5], hf1, acc2, 0, 0, 0); \
    acc3 = __builtin_amdgcn_mfma_f32_16x16x32_bf16(WFC[7], hf1, acc3, 0, 0, 0); \
    float s = 0.f, sq = 0.f;                                                   \
    _Pragma("unroll")                                                          \
    for (int rg = 0; rg < 4; ++rg) {                                           \
      float z0 = fmaxf(acc0[rg], 0.f); outv[rg] = z0;                          \
      float z1 = fmaxf(acc1[rg], 0.f); outv[4 + rg] = z1;                      \
      float z2 = fmaxf(acc2[rg], 0.f); outv[8 + rg] = z2;                      \
      float z3 = fmaxf(acc3[rg], 0.f); outv[12 + rg] = z3;                     \
      s += (z0 + z1) + (z2 + z3);                                              \
      sq = fmaf(z0, z0, sq); sq = fmaf(z1, z1, sq);                            \
      sq = fmaf(z2, z2, sq); sq = fmaf(z3, z3, sq);                            \
    }                                                                          \
    s = red4(s); sq = red4(sq);                                                \
    const float mean = s * 0.015625f;                                          \
    const float var = fmaf(sq, 0.015625f, -mean * mean);                       \
    const float rs = rsqrtf(var + 1e-5f);                                      \
    const float cc = -mean * rs;                                               \
    if (gb) {                                                                  \
      _Pragma("unroll")                                                        \
      for (int mt = 0; mt < 4; ++mt) {                                         \
        float4 gg = *(const float4*)(ln_g + m * 64 + mt * 16 + lg * 4);        \
        float4 bb = *(const float4*)(ln_b + m * 64 + mt * 16 + lg * 4);        \
        outv[mt * 4 + 0] = fmaf(fmaf(outv[mt * 4 + 0], rs, cc), gg.x, bb.x);   \
        outv[mt * 4 + 1] = fmaf(fmaf(outv[mt * 4 + 1], rs, cc), gg.y, bb.y);   \
        outv[mt * 4 + 2] = fmaf(fmaf(outv[mt * 4 + 2], rs, cc), gg.z, bb.z);   \
        outv[mt * 4 + 3] = fmaf(fmaf(outv[mt * 4 + 3], rs, cc), gg.w, bb.w);   \
      }                                                                        \
    } else {                                                                   \
      _Pragma("unroll")                                                        \
      for (int i = 0; i < 16; ++i) outv[i] = fmaf(outv[i], rs, cc);            \
    }                                                                          \
    if (m < 511) {                                                             \
      unsigned Q0 = pk2bf(outv[0], outv[1]),   Q1 = pk2bf(outv[2], outv[3]);   \
      unsigned Q2 = pk2bf(outv[4], outv[5]),   Q3 = pk2bf(outv[6], outv[7]);   \
      unsigned Q4 = pk2bf(outv[8], outv[9]),   Q5 = pk2bf(outv[10], outv[11]); \
      unsigned Q6 = pk2bf(outv[12], outv[13]), Q7 = pk2bf(outv[14], outv[15]); \
      x32<R32>(Q0, Q2); x16<R16>(Q0, Q2);                                      \
      x32<R32>(Q1, Q3); x16<R16>(Q1, Q3);                                      \
      x32<R32>(Q4, Q6); x16<R16>(Q4, Q6);                                      \
      x32<R32>(Q5, Q7); x16<R16>(Q5, Q7);                                      \
      union { unsigned d[4]; short8 s8; } uu0, uu1;                            \
      uu0.d[0] = Q0; uu0.d[1] = Q1; uu0.d[2] = Q2; uu0.d[3] = Q3;              \
      uu1.d[0] = Q4; uu1.d[1] = Q5; uu1.d[2] = Q6; uu1.d[3] = Q7;              \
      hf0 = uu0.s8; hf1 = uu1.s8;                                              \
    }                                                                          \
    if (BAR) {                                                                 \
      asm volatile("s_waitcnt lgkmcnt(0)" ::: "memory");                       \
      __builtin_amdgcn_s_barrier();                                            \
    }                                                                          \
  }

template<bool R16, bool R32>
__device__ void kscan_body(const float* __restrict__ x,
                           const short* __restrict__ wbf,
                           const float* __restrict__ ln_g,
                           const float* __restrict__ ln_b,
                           int gb, float* __restrict__ mem_out,
                           char* __restrict__ wldsc) {
  const int t = threadIdx.x;
  const int lane = t & 63;
  const int wv = t >> 6;
  const int lcol = lane & 15;
  const int lg = lane >> 4;
  const int blk = blockIdx.x;
  const int r = wv * 16 + lcol;          // this lane's h row (0..127)

  const int wsw = (lcol & 7) << 4;
  int wrd[8];                            // A-frag offsets within a slot
#pragma unroll
  for (int mt = 0; mt < 4; ++mt) {
    wrd[mt * 2]     = mt * 2048 + lcol * 128 + ((lg * 16) ^ wsw);
    wrd[mt * 2 + 1] = mt * 2048 + lcol * 128 + ((lg * 16 + 64) ^ wsw);
  }
  const int so0 = (t * 16) ^ ((((t * 16) >> 7) & 7) << 4);
  const int4* wp = (const int4*)wbf;

  // initial h B-fragments straight from x
  short8 hf0, hf1;
  {
    const float4* xr = (const float4*)(x + ((size_t)(blk * 128 + r)) * 64);
    float4 a0 = xr[lg * 2], a1 = xr[lg * 2 + 1];
    float4 b0 = xr[8 + lg * 2], b1 = xr[8 + lg * 2 + 1];
    union { unsigned d[4]; short8 s8; } u0, u1;
    u0.d[0] = pk2bf(a0.x, a0.y); u0.d[1] = pk2bf(a0.z, a0.w);
    u0.d[2] = pk2bf(a1.x, a1.y); u0.d[3] = pk2bf(a1.z, a1.w);
    u1.d[0] = pk2bf(b0.x, b0.y); u1.d[1] = pk2bf(b0.z, b0.w);
    u1.d[2] = pk2bf(b1.x, b1.y); u1.d[3] = pk2bf(b1.z, b1.w);
    hf0 = u0.s8; hf1 = u1.s8;
  }
  // prologue: stage W[0..4] into slots 0..4; preload gA = W[5..8]
#pragma unroll
  for (int sslot = 0; sslot < 5; ++sslot) {
    int4 w = wp[(size_t)sslot * 512 + t];
    *(int4*)(wldsc + sslot * 8192 + so0) = w;
  }
  int4 gA0 = wp[(size_t)5 * 512 + t], gA1 = wp[(size_t)6 * 512 + t];
  int4 gA2 = wp[(size_t)7 * 512 + t], gA3 = wp[(size_t)8 * 512 + t];
  int4 gB0, gB1, gB2, gB3;
  __syncthreads();

  short8 wfA[8], wfB[8];
#pragma unroll
  for (int i = 0; i < 8; ++i) wfA[i] = *(const short8*)(wldsc + wrd[i]);  // slot 0
  // slot 0 is rewritten (W[8]) during the first superstep -> finish reads first
  asm volatile("s_waitcnt lgkmcnt(0)" ::: "memory");
  __builtin_amdgcn_s_barrier();

  const f32x4 z4 = {0.f, 0.f, 0.f, 0.f};
  float outv[16];

  for (int mb = 0; mb < 512; mb += 8) {
    // superstep A: steps mb..mb+3, write W[mb+5..8] (slots 5,6,7,0), load gB=W[mb+9..12]
    KS(0, wfA, wfB, gA0, gB0, 0)
    KS(1, wfB, wfA, gA1, gB1, 0)
    KS(2, wfA, wfB, gA2, gB2, 0)
    KS(3, wfB, wfA, gA3, gB3, 1)
    // superstep B: steps mb+4..mb+7, write W[mb+9..12] (slots 1,2,3,4), load gA=W[mb+13..16]
    KS(4, wfA, wfB, gB0, gA0, 0)
    KS(5, wfB, wfA, gB1, gA1, 0)
    KS(6, wfA, wfB, gB2, gA2, 0)
    KS(7, wfB, wfA, gB3, gA3, 1)
  }

  // epilogue: outv holds the final LN output (f32) for row r
  float* mo = mem_out + ((size_t)(blk * 128 + r)) * 64;
#pragma unroll
  for (int mt = 0; mt < 4; ++mt)
    *(float4*)(mo + mt * 16 + lg * 4) =
        make_float4(outv[mt * 4], outv[mt * 4 + 1], outv[mt * 4 + 2], outv[mt * 4 + 3]);
}

__global__ __launch_bounds__(512, 2) void kscan(
    const float* __restrict__ x, const short* __restrict__ wbf,
    const float* __restrict__ ln_g, const float* __restrict__ ln_b,
    const int* __restrict__ flagp, float* __restrict__ mem_out) {
  __shared__ short wlds[8][64 * 64];     // W ring, bf16, XOR-swizzled, 64 KiB
  const int lane = threadIdx.x & 63;
  const int gb = *flagp;
  // Probe the HW direction of permlane{16,32}_swap (uniform, deterministic).
  unsigned pa = (unsigned)lane, pb = 1000u + (unsigned)lane;
  pl16raw_ec(pa, pb);
  const bool r16 = (__builtin_amdgcn_readfirstlane((int)pa) != 0);
  unsigned qa = (unsigned)lane, qb = 2000u + (unsigned)lane;
  pl32raw_ec(qa, qb);
  const bool r32 = (__builtin_amdgcn_readfirstlane((int)qa) != 0);
  char* ldsb = (char*)&wlds[0][0];
  if (!r16) {
    if (!r32) kscan_body<false, false>(x, wbf, ln_g, ln_b, gb, mem_out, ldsb);
    else      kscan_body<false, true >(x, wbf, ln_g, ln_b, gb, mem_out, ldsb);
  } else {
    if (!r32) kscan_body<true, false >(x, wbf, ln_g, ln_b, gb, mem_out, ldsb);
    else      kscan_body<true, true  >(x, wbf, ln_g, ln_b, gb, mem_out, ldsb);
  }
}

// ---------------- kh/vh = mem_out @ W{k,v}_eff^T + b, stored bf16 ----------
__global__ __launch_bounds__(256) void kkv(const float* __restrict__ mem_out,
                                           const float* __restrict__ weff,
                                           const float* __restrict__ beff,
                                           short* __restrict__ khvh) {
  __shared__ short kvs[128 * 128];
  const int t = threadIdx.x;
  const int nl = t >> 1;
  const int jh = (t & 1) * 32;
  const int n = blockIdx.x * 128 + nl;
  float mo[64];
  const float4* mop = (const float4*)(mem_out + (size_t)n * 64);
#pragma unroll
  for (int c = 0; c < 16; ++c) {
    float4 f = mop[c];
    mo[c * 4] = f.x; mo[c * 4 + 1] = f.y; mo[c * 4 + 2] = f.z; mo[c * 4 + 3] = f.w;
  }
  const float* wk = weff + 4096;
  const float* wvp = weff + 8192;
  const float* bk = beff + 64;
  const float* bv = beff + 128;
  for (int jj = 0; jj < 32; ++jj) {
    const int j = jh + jj;
    float ak = bk[j], av = bv[j];
    const float* wkr = wk + (size_t)j * 64;
    const float* wvr = wvp + (size_t)j * 64;
#pragma unroll 8
    for (int e = 0; e < 64; ++e) { ak = fmaf(mo[e], wkr[e], ak); av = fmaf(mo[e], wvr[e], av); }
    kvs[nl * 128 + j] = (short)f2bf1(ak);
    kvs[nl * 128 + 64 + j] = (short)f2bf1(av);
  }
  __syncthreads();
  int4* dst = (int4*)(khvh + (size_t)blockIdx.x * 16384);
  const int4* srcl = (const int4*)kvs;
#pragma unroll
  for (int c = 0; c < 8; ++c) dst[t + c * 256] = srcl[t + c * 256];
}

// ---------------- attention, atomic-free two-stage (f32 LDS tiles) --------
__global__ __launch_bounds__(512) void kattn2(const short* __restrict__ khvh,
                                              const float* __restrict__ qh,
                                              float* __restrict__ pO,
                                              float* __restrict__ pE) {
  __shared__ float kvf[64 * 128];   // 64-key tile, f32 (K|V), 32 KiB
  const int t = threadIdx.x;
  const int hh = t >> 6;
  const int ml = t & 63;
  const int c = blockIdx.x >> 2;
  const int mc = blockIdx.x & 3;
  const int m0 = mc * 128 + ml;
  const int m1 = m0 + 64;
  float q0[8], q1[8], o0[8], o1[8];
  float e0 = 0.f, e1 = 0.f;
  {
    const float4* qp0 = (const float4*)(qh + (size_t)m0 * 64 + hh * 8);
    const float4* qp1 = (const float4*)(qh + (size_t)m1 * 64 + hh * 8);
    float4 a = qp0[0], b = qp0[1], cc2 = qp1[0], d2 = qp1[1];
    q0[0]=a.x; q0[1]=a.y; q0[2]=a.z; q0[3]=a.w; q0[4]=b.x; q0[5]=b.y; q0[6]=b.z; q0[7]=b.w;
    q1[0]=cc2.x; q1[1]=cc2.y; q1[2]=cc2.z; q1[3]=cc2.w; q1[4]=d2.x; q1[5]=d2.y; q1[6]=d2.z; q1[7]=d2.w;
#pragma unroll
    for (int d = 0; d < 8; ++d) { o0[d] = 0.f; o1[d] = 0.f; }
  }
  for (int tile = 0; tile < 8; ++tile) {
    if (tile) __syncthreads();
    const int4* src = (const int4*)(khvh + ((size_t)(c * 512 + tile * 64)) * 128);
#pragma unroll
    for (int u = 0; u < 2; ++u) {
      int4 rawv = src[t + u * 512];
      float* dp = kvf + ((size_t)(t + u * 512)) * 8;
      unsigned w0 = (unsigned)rawv.x, w1 = (unsigned)rawv.y;
      unsigned w2 = (unsigned)rawv.z, w3 = (unsigned)rawv.w;
      float4 f0, f1;
      f0.x = bf2f((ushort_t)(w0 & 0xffffu)); f0.y = bf2f((ushort_t)(w0 >> 16));
      f0.z = bf2f((ushort_t)(w1 & 0xffffu)); f0.w = bf2f((ushort_t)(w1 >> 16));
      f1.x = bf2f((ushort_t)(w2 & 0xffffu)); f1.y = bf2f((ushort_t)(w2 >> 16));
      f1.z = bf2f((ushort_t)(w3 & 0xffffu)); f1.w = bf2f((ushort_t)(w3 >> 16));
      *(float4*)dp = f0; *(float4*)(dp + 4) = f1;
    }
    __syncthreads();
    for (int n = 0; n < 64; ++n) {
      const float4 ka = *(const float4*)(kvf + n * 128 + hh * 8);
      const float4 kb = *(const float4*)(kvf + n * 128 + hh * 8 + 4);
      const float4 va = *(const float4*)(kvf + n * 128 + 64 + hh * 8);
      const float4 vb = *(const float4*)(kvf + n * 128 + 64 + hh * 8 + 4);
      float s0 = 0.f, s1 = 0.f;
      s0 = fmaf(q0[0], ka.x, s0); s0 = fmaf(q0[1], ka.y, s0);
      s0 = fmaf(q0[2], ka.z, s0); s0 = fmaf(q0[3], ka.w, s0);
      s0 = fmaf(q0[4], kb.x, s0); s0 = fmaf(q0[5], kb.y, s0);
      s0 = fmaf(q0[6], kb.z, s0); s0 = fmaf(q0[7], kb.w, s0);
      s1 = fmaf(q1[0], ka.x, s1); s1 = fmaf(q1[1], ka.y, s1);
      s1 = fmaf(q1[2], ka.z, s1); s1 = fmaf(q1[3], ka.w, s1);
      s1 = fmaf(q1[4], kb.x, s1); s1 = fmaf(q1[5], kb.y, s1);
      s1 = fmaf(q1[6], kb.z, s1); s1 = fmaf(q1[7], kb.w, s1);
      float p0 = __expf(s0), p1 = __expf(s1);
      e0 += p0; e1 += p1;
      o0[0] = fmaf(p0, va.x, o0[0]); o0[1] = fmaf(p0, va.y, o0[1]);
      o0[2] = fmaf(p0, va.z, o0[2]); o0[3] = fmaf(p0, va.w, o0[3]);
      o0[4] = fmaf(p0, vb.x, o0[4]); o0[5] = fmaf(p0, vb.y, o0[5]);
      o0[6] = fmaf(p0, vb.z, o0[6]); o0[7] = fmaf(p0, vb.w, o0[7]);
      o1[0] = fmaf(p1, va.x, o1[0]); o1[1] = fmaf(p1, va.y, o1[1]);
      o1[2] = fmaf(p1, va.z, o1[2]); o1[3] = fmaf(p1, va.w, o1[3]);
      o1[4] = fmaf(p1, vb.x, o1[4]); o1[5] = fmaf(p1, vb.y, o1[5]);
      o1[6] = fmaf(p1, vb.z, o1[6]); o1[7] = fmaf(p1, vb.w, o1[7]);
    }
  }
  const int idx0 = hh * 512 + m0;
  const int idx1 = hh * 512 + m1;
  pE[(size_t)c * 4096 + idx0] = e0;
  pE[(size_t)c * 4096 + idx1] = e1;
  float4* po0 = (float4*)(pO + (size_t)c * 32768 + (size_t)idx0 * 8);
  float4* po1 = (float4*)(pO + (size_t)c * 32768 + (size_t)idx1 * 8);
  po0[0] = make_float4(o0[0], o0[1], o0[2], o0[3]);
  po0[1] = make_float4(o0[4], o0[5], o0[6], o0[7]);
  po1[0] = make_float4(o1[0], o1[1], o1[2], o1[3]);
  po1[1] = make_float4(o1[4], o1[5], o1[6], o1[7]);
}

// ---------------- reduce partials -> oacc / esum ----------------
__global__ __launch_bounds__(256) void kred(const float* __restrict__ pO,
                                            const float* __restrict__ pE,
                                            float* __restrict__ oacc,
                                            float* __restrict__ esum) {
  int gid = blockIdx.x * 256 + threadIdx.x;
  if (gid < 32768) {
    float s = 0.f;
#pragma unroll 8
    for (int ci = 0; ci < NCH; ++ci) s += pO[(size_t)ci * 32768 + gid];
    oacc[gid] = s;
  } else if (gid < 36864) {
    int j = gid - 32768;
    float s = 0.f;
#pragma unroll 8
    for (int ci = 0; ci < NCH; ++ci) s += pE[(size_t)ci * 4096 + j];
    esum[j] = s;
  }
}

// ---------------- attention fallback (atomics) if ws too small ----------
__global__ __launch_bounds__(512) void kattn_atomic(const short* __restrict__ khvh,
                                                    const float* __restrict__ qh,
                                                    float* __restrict__ oacc,
                                                    float* __restrict__ esum) {
  __shared__ short kv[128 * 128];
  const int t = threadIdx.x;
  const int hh = t >> 6;
  const int ms = t & 63;
  {
    const int4* src = (const int4*)(khvh + (size_t)blockIdx.x * 16384);
    int4* d = (int4*)kv;
#pragma unroll
    for (int c = 0; c < 4; ++c) d[t + c * 512] = src[t + c * 512];
  }
  __syncthreads();
  float q[8][8], o[8][8], es[8];
#pragma unroll
  for (int i = 0; i < 8; ++i) {
    const float4* qp = (const float4*)(qh + ((size_t)(ms + i * 64)) * 64 + hh * 8);
    float4 q0 = qp[0], q1 = qp[1];
    q[i][0] = q0.x; q[i][1] = q0.y; q[i][2] = q0.z; q[i][3] = q0.w;
    q[i][4] = q1.x; q[i][5] = q1.y; q[i][6] = q1.z; q[i][7] = q1.w;
    es[i] = 0.f;
#pragma unroll
    for (int d = 0; d < 8; ++d) o[i][d] = 0.f;
  }
  for (int n = 0; n < 128; ++n) {
    const short8 kraw = *(const short8*)(kv + n * 128 + hh * 8);
    const short8 vraw = *(const short8*)(kv + n * 128 + 64 + hh * 8);
    float kf[8], vf[8];
#pragma unroll
    for (int d = 0; d < 8; ++d) {
      kf[d] = bf2f((ushort_t)kraw[d]);
      vf[d] = bf2f((ushort_t)vraw[d]);
    }
#pragma unroll
    for (int i = 0; i < 8; ++i) {
      float s = 0.f;
#pragma unroll
      for (int d = 0; d < 8; ++d) s = fmaf(q[i][d], kf[d], s);
      float p = __expf(s);
      es[i] += p;
#pragma unroll
      for (int d = 0; d < 8; ++d) o[i][d] = fmaf(p, vf[d], o[i][d]);
    }
  }
#pragma unroll
  for (int i = 0; i < 8; ++i) {
    const int m = ms + i * 64;
    atomicAdd(&esum[hh * 512 + m], es[i]);
#pragma unroll
    for (int d = 0; d < 8; ++d) atomicAdd(&oacc[((size_t)(hh * 512 + m)) * 8 + d], o[i][d]);
  }
}

// ---------------- fused ratio + final: out1 = mem_w * (1 + attn/avg) ------
__global__ __launch_bounds__(256) void kfr(const float* __restrict__ oacc,
                                           const float* __restrict__ esum,
                                           const float* __restrict__ out_w,
                                           const float* __restrict__ out_b,
                                           const float* __restrict__ avg,
                                           const float* __restrict__ mem_w,
                                           float* __restrict__ out1) {
  __shared__ float rat[64];
  const int t = threadIdx.x;
  const int m = blockIdx.x;           // 512 blocks, one per memory slot
  if (t < 64) {
    const int e = t;
    float of[64];
#pragma unroll
    for (int h = 0; h < 8; ++h) {
      float inv = 1.f / esum[h * 512 + m];
      const float* op = oacc + ((size_t)(h * 512 + m)) * 8;
#pragma unroll
      for (int d = 0; d < 8; ++d) of[h * 8 + d] = op[d] * inv;
    }
    float a = out_b[e];
    const float* wr = out_w + (size_t)e * 64;
#pragma unroll 8
    for (int j = 0; j < 64; ++j) a = fmaf(of[j], wr[j], a);
    rat[e] = 1.f + a / avg[m * 64 + e];
  }
  __syncthreads();
  const float4* src = (const float4*)(mem_w + (size_t)m * 4096);
  float4* dst = (float4*)(out1 + (size_t)m * 4096);
#pragma unroll
  for (int c = 0; c < 4; ++c) {
    int idx = t + c * 256;            // 1024 float4 per m
    float rr = rat[idx >> 4];
    float4 w = src[idx];
    dst[idx] = make_float4(w.x * rr, w.y * rr, w.z * rr, w.w * rr);
  }
}

extern "C" void kernel_launch(void* const* d_in, const int* in_sizes, int n_in,
                              void* d_out, int out_size, void* d_ws, size_t ws_size,
                              hipStream_t stream) {
  (void)in_sizes; (void)n_in; (void)out_size;
  const float* x         = (const float*)d_in[0];
  const float* mem_w     = (const float*)d_in[1];
  const float* ln_g      = (const float*)d_in[2];
  const float* ln_b      = (const float*)d_in[3];
  const float* Wq        = (const float*)d_in[4];
  const float* bq        = (const float*)d_in[5];
  const float* Wk        = (const float*)d_in[6];
  const float* bk        = (const float*)d_in[7];
  const float* Wv        = (const float*)d_in[8];
  const float* bv        = (const float*)d_in[9];
  const float* in_proj_w = (const float*)d_in[10];
  const float* in_proj_b = (const float*)d_in[11];
  const float* out_w     = (const float*)d_in[12];
  const float* out_b     = (const float*)d_in[13];

  float* dout = (float*)d_out;
  char* ws = (char*)d_ws;
  short* wbf   = (short*)(ws + WBF_OFF);
  short* khvh  = (short*)(ws + KVH_OFF);
  float* qh    = (float*)(ws + QH_OFF);
  float* avg   = (float*)(ws + AVG_OFF);
  float* weff  = (float*)(ws + WEFF_OFF);
  float* beff  = (float*)(ws + BEFF_OFF);
  float* oacc  = (float*)(ws + OACC_OFF);
  float* esum  = (float*)(ws + ESUM_OFF);
  int*   flag  = (int*)(ws + FLAG_OFF);
  float* pO    = (float*)(ws + PO_OFF);
  float* pE    = (float*)(ws + PE_OFF);

  float* mem_out = dout;              // output 0: (32768, 64)
  float* out1    = dout + 2097152;    // output 1: (512, 64, 64)

  const bool use_part = (ws_size >= WS_NEED);   // host-constant: graph-safe

  hipMemsetAsync(flag, 0, 4, stream);
  kpre<<<305, 256, 0, stream>>>(mem_w, ln_g, ln_b, in_proj_w, in_proj_b,
                                Wq, bq, Wk, bk, Wv, bv, wbf, avg, weff, beff, flag);
  kqh<<<128, 256, 0, stream>>>(avg, weff, beff, qh);
  kscan<<<256, 512, 0, stream>>>(x, wbf, ln_g, ln_b, flag, mem_out);
  kkv<<<256, 256, 0, stream>>>(mem_out, weff, beff, khvh);
  if (use_part) {
    kattn2<<<NCH * 4, 512, 0, stream>>>(khvh, qh, pO, pE);
    kred<<<144, 256, 0, stream>>>(pO, pE, oacc, esum);
  } else {
    kinit<<<144, 256, 0, stream>>>(oacc);
    kattn_atomic<<<256, 512, 0, stream>>>(khvh, qh, oacc, esum);
  }
  kfr<<<512, 256, 0, stream>>>(oacc, esum, out_w, out_b, avg, mem_w, out1);
}

// Round 9
// 554.472 us; speedup vs baseline: 1.1331x; 1.1090x over previous
//
#include <hip/hip_runtime.h>
#include <hip/hip_bf16.h>
#include <cstdint>
#include <cstddef>

typedef __attribute__((ext_vector_type(8))) short short8;
typedef __attribute__((ext_vector_type(4))) float f32x4;
typedef unsigned short ushort_t;

// ---------------- ws layout (bytes) ----------------
#define WBF_OFF   0u            // 512*64*64 bf16 (linear) = 4 MiB
#define KVH_OFF   4194304u      // 32768*128 bf16 (kh|vh per row) = 8 MiB
#define QH_OFF    12582912u     // 512*64 f32 (pre-scaled by 1/sqrt(8))
#define AVG_OFF   12713984u     // 512*64 f32 row means of mem_w
#define WEFF_OFF  12845056u     // 3 * 64*64 f32 combined projections
#define BEFF_OFF  12894208u     // 3 * 64 f32 combined biases
#define OACC_OFF  12894976u     // 8*512*8 f32 attention numerator (fallback)
#define ESUM_OFF  13026048u     // 8*512 f32 softmax denominator (fallback)
#define FLAG_OFF  13173504u     // int: nontrivial ln_g/ln_b flag
#define PO_OFF    13180928u     // 64 chunks * 32768 f32 partial O = 8 MiB
#define PE_OFF    21569536u     // 64 chunks * 4096 f32 partial esum = 1 MiB
#define WS_NEED   22618112ull   // bytes required for the partial scheme
#define NCH 64                  // key chunks (512 keys each)

__device__ __forceinline__ float bf2f(ushort_t u) {
  union { unsigned int i; float f; } c; c.i = ((unsigned int)u) << 16; return c.f;
}
// Single-instruction packed f32->bf16 (RNE). No builtin on gfx950 (T12): inline asm.
__device__ __forceinline__ unsigned cvtpk(float a, float b) {
  unsigned r;
  asm("v_cvt_pk_bf16_f32 %0, %1, %2" : "=v"(r) : "v"(a), "v"(b));
  return r;
}
__device__ __forceinline__ ushort_t f2bf1(float f) {
  union { float f; unsigned int i; } c; c.f = f;
  unsigned int x = c.i;
  x += 0x7FFFu + ((x >> 16) & 1u);
  return (ushort_t)(x >> 16);
}
__device__ __forceinline__ float fbits(unsigned u) { return __builtin_bit_cast(float, u); }
__device__ __forceinline__ unsigned ubits(float f) { return __builtin_bit_cast(unsigned, f); }

// Raw gfx950 register-pair lane swaps (in-place on both operands).
__device__ __forceinline__ void pl16raw(unsigned &a, unsigned &b) {
  asm("v_permlane16_swap_b32 %0, %1" : "+v"(a), "+v"(b));
}
__device__ __forceinline__ void pl32raw(unsigned &a, unsigned &b) {
  asm("v_permlane32_swap_b32 %0, %1" : "+v"(a), "+v"(b));
}
__device__ __forceinline__ void pl16raw_ec(unsigned &a, unsigned &b) {
  asm("v_permlane16_swap_b32 %0, %1" : "+&v"(a), "+&v"(b));
}
__device__ __forceinline__ void pl32raw_ec(unsigned &a, unsigned &b) {
  asm("v_permlane32_swap_b32 %0, %1" : "+&v"(a), "+&v"(b));
}
template<bool REV> __device__ __forceinline__ void x16(unsigned &a, unsigned &b) {
  if (!REV) pl16raw(a, b); else pl16raw(b, a);
}
template<bool REV> __device__ __forceinline__ void x32(unsigned &a, unsigned &b) {
  if (!REV) pl32raw(a, b); else pl32raw(b, a);
}
// Sum over the 4-lane group {c, c+16, c+32, c+48}; direction-agnostic.
// The asm("":"+v") copy-force is REQUIRED: both swap operands carry the same
// SSA value, and without it regalloc can coalesce them into one register ->
// v_permlane16_swap R,R self-swap -> garbage (R8 regression).
__device__ __forceinline__ float red4(float v) {
  unsigned a = ubits(v), b = a;
  asm("" : "+v"(b));
  pl16raw_ec(a, b);
  float w = fbits(a) + fbits(b);
  unsigned c = ubits(w), d = c;
  asm("" : "+v"(d));
  pl32raw_ec(c, d);
  return fbits(c) + fbits(d);
}

// ---------------- init (fallback only): zero accumulators ----------------
__global__ __launch_bounds__(256) void kinit(float* oacc) {
  int gid = blockIdx.x * 256 + threadIdx.x;
  if (gid < 36864) oacc[gid] = 0.f;   // oacc (32768) + esum (4096), contiguous
}

// ---------------- fused preamble: flag + prep + weff/beff ----------------
__global__ __launch_bounds__(256) void kpre(const float* __restrict__ mem_w,
                                            const float* __restrict__ ln_g,
                                            const float* __restrict__ ln_b,
                                            const float* __restrict__ in_proj_w,
                                            const float* __restrict__ in_proj_b,
                                            const float* __restrict__ Wq, const float* __restrict__ bq,
                                            const float* __restrict__ Wk, const float* __restrict__ bk,
                                            const float* __restrict__ Wv, const float* __restrict__ bv,
                                            short* __restrict__ wbf,
                                            float* __restrict__ avg,
                                            float* __restrict__ weff,
                                            float* __restrict__ beff,
                                            int* __restrict__ flag) {
  int gid = blockIdx.x * 256 + threadIdx.x;
  if (gid < 32768) {
    const float4* src = (const float4*)(mem_w + (size_t)gid * 64);
    int4* dst = (int4*)(wbf + (size_t)gid * 64);
    float sum = 0.f;
#pragma unroll
    for (int c = 0; c < 8; ++c) {
      float4 f0 = src[c * 2], f1 = src[c * 2 + 1];
      sum += f0.x + f0.y + f0.z + f0.w + f1.x + f1.y + f1.z + f1.w;
      int4 pk;
      pk.x = (int)cvtpk(f0.x, f0.y); pk.y = (int)cvtpk(f0.z, f0.w);
      pk.z = (int)cvtpk(f1.x, f1.y); pk.w = (int)cvtpk(f1.z, f1.w);
      dst[c] = pk;
    }
    avg[gid] = sum * 0.015625f;
  } else if (gid < 65536) {
    int j = gid - 32768;
    if (ln_g[j] != 1.0f || ln_b[j] != 0.0f) atomicOr(flag, 1);
  } else if (gid < 77824) {
    int k = gid - 65536;
    int mat = k >> 12, j = (k >> 6) & 63, e = k & 63;
    const float* Wi = in_proj_w + ((size_t)(mat * 64 + j)) * 64;
    const float* Wx = (mat == 0) ? Wq : ((mat == 1) ? Wk : Wv);
    float acc = 0.f;
#pragma unroll 8
    for (int tt = 0; tt < 64; ++tt) acc = fmaf(Wi[tt], Wx[tt * 64 + e], acc);
    weff[k] = acc;
  } else if (gid < 78016) {
    int k = gid - 77824; int mat = k >> 6, j = k & 63;
    const float* Wi = in_proj_w + ((size_t)(mat * 64 + j)) * 64;
    const float* bx = (mat == 0) ? bq : ((mat == 1) ? bk : bv);
    float acc = in_proj_b[mat * 64 + j];
#pragma unroll 8
    for (int tt = 0; tt < 64; ++tt) acc = fmaf(Wi[tt], bx[tt], acc);
    beff[k] = acc;
  }
}

// ---------------- qh = avg_w @ Wq_eff^T + bq_eff, scaled 1/sqrt(DH) --------
__global__ __launch_bounds__(256) void kqh(const float* __restrict__ avg,
                                           const float* __restrict__ weff,
                                           const float* __restrict__ beff,
                                           float* __restrict__ qh) {
  int gid = blockIdx.x * 256 + threadIdx.x;   // 32768 = 512*64
  int m = gid >> 6, j = gid & 63;
  const float* ar = avg + (size_t)m * 64;
  const float* wr = weff + (size_t)j * 64;
  float acc = beff[j];
#pragma unroll 8
  for (int e = 0; e < 64; ++e) acc = fmaf(ar[e], wr[e], acc);
  qh[gid] = acc * 0.35355339059327373f;
}

// ---------------- the sequential memory scan (register-resident h) --------
// 512 thr (8 waves), 128 rows/block, 256 blocks. h in registers; C-frag ->
// next B-frag via v_cvt_pk_bf16_f32 + permlane swaps. W in 4-slot LDS ring;
// barrier every step. The ds_write is issued FIRST each step, so the
// pre-barrier wait is lgkmcnt(8) (DS retires in order -> write drained; the
// 8 frag reads ride across the barrier; their slot is rewritten 3 barriers
// later and the compiler inserts waits before their MFMA use).
#define KSTEP(PP, WFC, WFN, GC, GN)                                            \
  {                                                                            \
    const int m = mb + PP;                                                     \
    if (m + 2 < 512) *(int4*)((char*)wlds[(PP + 2) & 3] + so0) = GC;           \
    if (m + 3 < 512) GN = ((const int4*)wbf)[(m + 3) * 512 + t];               \
    if (m + 1 < 512) {                                                         \
      const char* rb = (const char*)wlds[(PP + 1) & 3];                        \
      _Pragma("unroll")                                                        \
      for (int i = 0; i < 8; ++i) WFN[i] = *(const short8*)(rb + wrd[i]);      \
    }                                                                          \
    f32x4 acc0 = __builtin_amdgcn_mfma_f32_16x16x32_bf16(WFC[0], hf0, z4, 0, 0, 0); \
    f32x4 acc1 = __builtin_amdgcn_mfma_f32_16x16x32_bf16(WFC[2], hf0, z4, 0, 0, 0); \
    f32x4 acc2 = __builtin_amdgcn_mfma_f32_16x16x32_bf16(WFC[4], hf0, z4, 0, 0, 0); \
    f32x4 acc3 = __builtin_amdgcn_mfma_f32_16x16x32_bf16(WFC[6], hf0, z4, 0, 0, 0); \
    acc0 = __builtin_amdgcn_mfma_f32_16x16x32_bf16(WFC[1], hf1, acc0, 0, 0, 0); \
    acc1 = __builtin_amdgcn_mfma_f32_16x16x32_bf16(WFC[3], hf1, acc1, 0, 0, 0); \
    acc2 = __builtin_amdgcn_mfma_f32_16x16x32_bf16(WFC[5], hf1, acc2, 0, 0, 0); \
    acc3 = __builtin_amdgcn_mfma_f32_16x16x32_bf16(WFC[7], hf1, acc3, 0, 0, 0); \
    _Pragma("unroll")                                                          \
    for (int rg = 0; rg < 4; ++rg) {                                           \
      outv[rg]      = fmaxf(acc0[rg], 0.f);                                    \
      outv[4 + rg]  = fmaxf(acc1[rg], 0.f);                                    \
      outv[8 + rg]  = fmaxf(acc2[rg], 0.f);                                    \
      outv[12 + rg] = fmaxf(acc3[rg], 0.f);                                    \
    }                                                                          \
    float s = (((outv[0] + outv[1]) + (outv[2] + outv[3]))                     \
             + ((outv[4] + outv[5]) + (outv[6] + outv[7])))                    \
            + (((outv[8] + outv[9]) + (outv[10] + outv[11]))                   \
             + ((outv[12] + outv[13]) + (outv[14] + outv[15])));               \
    float qa = fmaf(outv[3], outv[3], fmaf(outv[2], outv[2],                   \
               fmaf(outv[1], outv[1], outv[0] * outv[0])));                    \
    float qb = fmaf(outv[7], outv[7], fmaf(outv[6], outv[6],                   \
               fmaf(outv[5], outv[5], outv[4] * outv[4])));                    \
    float qc = fmaf(outv[11], outv[11], fmaf(outv[10], outv[10],               \
               fmaf(outv[9], outv[9], outv[8] * outv[8])));                    \
    float qd = fmaf(outv[15], outv[15], fmaf(outv[14], outv[14],               \
               fmaf(outv[13], outv[13], outv[12] * outv[12])));                \
    float sq = (qa + qb) + (qc + qd);                                          \
    s = red4(s); sq = red4(sq);                                                \
    const float mean = s * 0.015625f;                                          \
    const float var = fmaf(sq, 0.015625f, -mean * mean);                       \
    const float rs = rsqrtf(var + 1e-5f);                                      \
    const float cc = -mean * rs;                                               \
    if (gb) {                                                                  \
      _Pragma("unroll")                                                        \
      for (int mt = 0; mt < 4; ++mt) {                                         \
        float4 gg = *(const float4*)(ln_g + m * 64 + mt * 16 + lg * 4);        \
        float4 bb = *(const float4*)(ln_b + m * 64 + mt * 16 + lg * 4);        \
        outv[mt * 4 + 0] = fmaf(fmaf(outv[mt * 4 + 0], rs, cc), gg.x, bb.x);   \
        outv[mt * 4 + 1] = fmaf(fmaf(outv[mt * 4 + 1], rs, cc), gg.y, bb.y);   \
        outv[mt * 4 + 2] = fmaf(fmaf(outv[mt * 4 + 2], rs, cc), gg.z, bb.z);   \
        outv[mt * 4 + 3] = fmaf(fmaf(outv[mt * 4 + 3], rs, cc), gg.w, bb.w);   \
      }                                                                        \
    } else {                                                                   \
      _Pragma("unroll")                                                        \
      for (int i = 0; i < 16; ++i) outv[i] = fmaf(outv[i], rs, cc);            \
    }                                                                          \
    if (m < 511) {                                                             \
      unsigned Q0 = cvtpk(outv[0], outv[1]),   Q1 = cvtpk(outv[2], outv[3]);   \
      unsigned Q2 = cvtpk(outv[4], outv[5]),   Q3 = cvtpk(outv[6], outv[7]);   \
      unsigned Q4 = cvtpk(outv[8], outv[9]),   Q5 = cvtpk(outv[10], outv[11]); \
      unsigned Q6 = cvtpk(outv[12], outv[13]), Q7 = cvtpk(outv[14], outv[15]); \
      x32<R32>(Q0, Q2); x16<R16>(Q0, Q2);                                      \
      x32<R32>(Q1, Q3); x16<R16>(Q1, Q3);                                      \
      x32<R32>(Q4, Q6); x16<R16>(Q4, Q6);                                      \
      x32<R32>(Q5, Q7); x16<R16>(Q5, Q7);                                      \
      union { unsigned d[4]; short8 s8; } uu0, uu1;                            \
      uu0.d[0] = Q0; uu0.d[1] = Q1; uu0.d[2] = Q2; uu0.d[3] = Q3;              \
      uu1.d[0] = Q4; uu1.d[1] = Q5; uu1.d[2] = Q6; uu1.d[3] = Q7;              \
      hf0 = uu0.s8; hf1 = uu1.s8;                                              \
    }                                                                          \
    asm volatile("s_waitcnt lgkmcnt(8)" ::: "memory");                         \
    __builtin_amdgcn_s_barrier();                                              \
  }

template<bool R16, bool R32>
__device__ void kscan_body(const float* __restrict__ x,
                           const short* __restrict__ wbf,
                           const float* __restrict__ ln_g,
                           const float* __restrict__ ln_b,
                           int gb, float* __restrict__ mem_out,
                           short* __restrict__ wldsb) {
  short (*wlds)[64 * 64] = (short (*)[64 * 64])wldsb;
  const int t = threadIdx.x;
  const int lane = t & 63;
  const int wv = t >> 6;
  const int lcol = lane & 15;
  const int lg = lane >> 4;
  const int blk = blockIdx.x;
  const int r = wv * 16 + lcol;          // this lane's h row (0..127)

  const int wsw = (lcol & 7) << 4;
  int wrd[8];                            // A-frag offsets [mt][khalf]
#pragma unroll
  for (int mt = 0; mt < 4; ++mt) {
    wrd[mt * 2]     = mt * 2048 + lcol * 128 + ((lg * 16) ^ wsw);
    wrd[mt * 2 + 1] = mt * 2048 + lcol * 128 + ((lg * 16 + 64) ^ wsw);
  }
  const int so0 = (t * 16) ^ ((((t * 16) >> 7) & 7) << 4);

  // initial h B-fragments straight from x
  short8 hf0, hf1;
  {
    const float4* xr = (const float4*)(x + ((size_t)(blk * 128 + r)) * 64);
    float4 a0 = xr[lg * 2], a1 = xr[lg * 2 + 1];
    float4 b0 = xr[8 + lg * 2], b1 = xr[8 + lg * 2 + 1];
    union { unsigned d[4]; short8 s8; } u0, u1;
    u0.d[0] = cvtpk(a0.x, a0.y); u0.d[1] = cvtpk(a0.z, a0.w);
    u0.d[2] = cvtpk(a1.x, a1.y); u0.d[3] = cvtpk(a1.z, a1.w);
    u1.d[0] = cvtpk(b0.x, b0.y); u1.d[1] = cvtpk(b0.z, b0.w);
    u1.d[2] = cvtpk(b1.x, b1.y); u1.d[3] = cvtpk(b1.z, b1.w);
    hf0 = u0.s8; hf1 = u1.s8;
  }
  // stage W[0] -> buf0, W[1] -> buf1; preload W[2] into a register
  {
    int4 w0 = ((const int4*)wbf)[t];
    int4 w1 = ((const int4*)wbf)[512 + t];
    *(int4*)((char*)wlds[0] + so0) = w0;
    *(int4*)((char*)wlds[1] + so0) = w1;
  }
  int4 g0 = ((const int4*)wbf)[1024 + t];
  int4 g1;
  __syncthreads();

  short8 wfA[8], wfB[8];
#pragma unroll
  for (int i = 0; i < 8; ++i) wfA[i] = *(const short8*)((const char*)wlds[0] + wrd[i]);

  const f32x4 z4 = {0.f, 0.f, 0.f, 0.f};
  float outv[16];

  for (int mb = 0; mb < 512; mb += 4) {
    KSTEP(0, wfA, wfB, g0, g1)
    KSTEP(1, wfB, wfA, g1, g0)
    KSTEP(2, wfA, wfB, g0, g1)
    KSTEP(3, wfB, wfA, g1, g0)
  }

  // epilogue: outv holds the final LN output (f32) for row r
  float* mo = mem_out + ((size_t)(blk * 128 + r)) * 64;
#pragma unroll
  for (int mt = 0; mt < 4; ++mt)
    *(float4*)(mo + mt * 16 + lg * 4) =
        make_float4(outv[mt * 4], outv[mt * 4 + 1], outv[mt * 4 + 2], outv[mt * 4 + 3]);
}

__global__ __launch_bounds__(512, 2) void kscan(
    const float* __restrict__ x, const short* __restrict__ wbf,
    const float* __restrict__ ln_g, const float* __restrict__ ln_b,
    const int* __restrict__ flagp, float* __restrict__ mem_out) {
  __shared__ short wlds[4][64 * 64];     // W ring, bf16, XOR-swizzled, 32 KiB
  const int lane = threadIdx.x & 63;
  const int gb = *flagp;
  // Probe the HW direction of permlane{16,32}_swap (uniform, deterministic).
  unsigned pa = (unsigned)lane, pb = 1000u + (unsigned)lane;
  pl16raw_ec(pa, pb);
  const bool r16 = (__builtin_amdgcn_readfirstlane((int)pa) != 0);
  unsigned qa = (unsigned)lane, qb = 2000u + (unsigned)lane;
  pl32raw_ec(qa, qb);
  const bool r32 = (__builtin_amdgcn_readfirstlane((int)qa) != 0);
  short* ldsb = &wlds[0][0];
  if (!r16) {
    if (!r32) kscan_body<false, false>(x, wbf, ln_g, ln_b, gb, mem_out, ldsb);
    else      kscan_body<false, true >(x, wbf, ln_g, ln_b, gb, mem_out, ldsb);
  } else {
    if (!r32) kscan_body<true, false >(x, wbf, ln_g, ln_b, gb, mem_out, ldsb);
    else      kscan_body<true, true  >(x, wbf, ln_g, ln_b, gb, mem_out, ldsb);
  }
}

// ---------------- kh/vh = mem_out @ W{k,v}_eff^T + b, stored bf16 ----------
__global__ __launch_bounds__(256) void kkv(const float* __restrict__ mem_out,
                                           const float* __restrict__ weff,
                                           const float* __restrict__ beff,
                                           short* __restrict__ khvh) {
  __shared__ short kvs[128 * 128];
  const int t = threadIdx.x;
  const int nl = t >> 1;
  const int jh = (t & 1) * 32;
  const int n = blockIdx.x * 128 + nl;
  float mo[64];
  const float4* mop = (const float4*)(mem_out + (size_t)n * 64);
#pragma unroll
  for (int c = 0; c < 16; ++c) {
    float4 f = mop[c];
    mo[c * 4] = f.x; mo[c * 4 + 1] = f.y; mo[c * 4 + 2] = f.z; mo[c * 4 + 3] = f.w;
  }
  const float* wk = weff + 4096;
  const float* wvp = weff + 8192;
  const float* bk = beff + 64;
  const float* bv = beff + 128;
  for (int jj = 0; jj < 32; ++jj) {
    const int j = jh + jj;
    float ak = bk[j], av = bv[j];
    const float* wkr = wk + (size_t)j * 64;
    const float* wvr = wvp + (size_t)j * 64;
#pragma unroll 8
    for (int e = 0; e < 64; ++e) { ak = fmaf(mo[e], wkr[e], ak); av = fmaf(mo[e], wvr[e], av); }
    kvs[nl * 128 + j] = (short)f2bf1(ak);
    kvs[nl * 128 + 64 + j] = (short)f2bf1(av);
  }
  __syncthreads();
  int4* dst = (int4*)(khvh + (size_t)blockIdx.x * 16384);
  const int4* srcl = (const int4*)kvs;
#pragma unroll
  for (int c = 0; c < 8; ++c) dst[t + c * 256] = srcl[t + c * 256];
}

// ---------------- attention, atomic-free two-stage (f32 LDS tiles) --------
__global__ __launch_bounds__(512) void kattn2(const short* __restrict__ khvh,
                                              const float* __restrict__ qh,
                                              float* __restrict__ pO,
                                              float* __restrict__ pE) {
  __shared__ float kvf[64 * 128];   // 64-key tile, f32 (K|V), 32 KiB
  const int t = threadIdx.x;
  const int hh = t >> 6;
  const int ml = t & 63;
  const int c = blockIdx.x >> 2;
  const int mc = blockIdx.x & 3;
  const int m0 = mc * 128 + ml;
  const int m1 = m0 + 64;
  float q0[8], q1[8], o0[8], o1[8];
  float e0 = 0.f, e1 = 0.f;
  {
    const float4* qp0 = (const float4*)(qh + (size_t)m0 * 64 + hh * 8);
    const float4* qp1 = (const float4*)(qh + (size_t)m1 * 64 + hh * 8);
    float4 a = qp0[0], b = qp0[1], cc2 = qp1[0], d2 = qp1[1];
    q0[0]=a.x; q0[1]=a.y; q0[2]=a.z; q0[3]=a.w; q0[4]=b.x; q0[5]=b.y; q0[6]=b.z; q0[7]=b.w;
    q1[0]=cc2.x; q1[1]=cc2.y; q1[2]=cc2.z; q1[3]=cc2.w; q1[4]=d2.x; q1[5]=d2.y; q1[6]=d2.z; q1[7]=d2.w;
#pragma unroll
    for (int d = 0; d < 8; ++d) { o0[d] = 0.f; o1[d] = 0.f; }
  }
  for (int tile = 0; tile < 8; ++tile) {
    if (tile) __syncthreads();
    const int4* src = (const int4*)(khvh + ((size_t)(c * 512 + tile * 64)) * 128);
#pragma unroll
    for (int u = 0; u < 2; ++u) {
      int4 rawv = src[t + u * 512];
      float* dp = kvf + ((size_t)(t + u * 512)) * 8;
      unsigned w0 = (unsigned)rawv.x, w1 = (unsigned)rawv.y;
      unsigned w2 = (unsigned)rawv.z, w3 = (unsigned)rawv.w;
      float4 f0, f1;
      f0.x = bf2f((ushort_t)(w0 & 0xffffu)); f0.y = bf2f((ushort_t)(w0 >> 16));
      f0.z = bf2f((ushort_t)(w1 & 0xffffu)); f0.w = bf2f((ushort_t)(w1 >> 16));
      f1.x = bf2f((ushort_t)(w2 & 0xffffu)); f1.y = bf2f((ushort_t)(w2 >> 16));
      f1.z = bf2f((ushort_t)(w3 & 0xffffu)); f1.w = bf2f((ushort_t)(w3 >> 16));
      *(float4*)dp = f0; *(float4*)(dp + 4) = f1;
    }
    __syncthreads();
    for (int n = 0; n < 64; ++n) {
      const float4 ka = *(const float4*)(kvf + n * 128 + hh * 8);
      const float4 kb = *(const float4*)(kvf + n * 128 + hh * 8 + 4);
      const float4 va = *(const float4*)(kvf + n * 128 + 64 + hh * 8);
      const float4 vb = *(const float4*)(kvf + n * 128 + 64 + hh * 8 + 4);
      float s0 = 0.f, s1 = 0.f;
      s0 = fmaf(q0[0], ka.x, s0); s0 = fmaf(q0[1], ka.y, s0);
      s0 = fmaf(q0[2], ka.z, s0); s0 = fmaf(q0[3], ka.w, s0);
      s0 = fmaf(q0[4], kb.x, s0); s0 = fmaf(q0[5], kb.y, s0);
      s0 = fmaf(q0[6], kb.z, s0); s0 = fmaf(q0[7], kb.w, s0);
      s1 = fmaf(q1[0], ka.x, s1); s1 = fmaf(q1[1], ka.y, s1);
      s1 = fmaf(q1[2], ka.z, s1); s1 = fmaf(q1[3], ka.w, s1);
      s1 = fmaf(q1[4], kb.x, s1); s1 = fmaf(q1[5], kb.y, s1);
      s1 = fmaf(q1[6], kb.z, s1); s1 = fmaf(q1[7], kb.w, s1);
      float p0 = __expf(s0), p1 = __expf(s1);
      e0 += p0; e1 += p1;
      o0[0] = fmaf(p0, va.x, o0[0]); o0[1] = fmaf(p0, va.y, o0[1]);
      o0[2] = fmaf(p0, va.z, o0[2]); o0[3] = fmaf(p0, va.w, o0[3]);
      o0[4] = fmaf(p0, vb.x, o0[4]); o0[5] = fmaf(p0, vb.y, o0[5]);
      o0[6] = fmaf(p0, vb.z, o0[6]); o0[7] = fmaf(p0, vb.w, o0[7]);
      o1[0] = fmaf(p1, va.x, o1[0]); o1[1] = fmaf(p1, va.y, o1[1]);
      o1[2] = fmaf(p1, va.z, o1[2]); o1[3] = fmaf(p1, va.w, o1[3]);
      o1[4] = fmaf(p1, vb.x, o1[4]); o1[5] = fmaf(p1, vb.y, o1[5]);
      o1[6] = fmaf(p1, vb.z, o1[6]); o1[7] = fmaf(p1, vb.w, o1[7]);
    }
  }
  const int idx0 = hh * 512 + m0;
  const int idx1 = hh * 512 + m1;
  pE[(size_t)c * 4096 + idx0] = e0;
  pE[(size_t)c * 4096 + idx1] = e1;
  float4* po0 = (float4*)(pO + (size_t)c * 32768 + (size_t)idx0 * 8);
  float4* po1 = (float4*)(pO + (size_t)c * 32768 + (size_t)idx1 * 8);
  po0[0] = make_float4(o0[0], o0[1], o0[2], o0[3]);
  po0[1] = make_float4(o0[4], o0[5], o0[6], o0[7]);
  po1[0] = make_float4(o1[0], o1[1], o1[2], o1[3]);
  po1[1] = make_float4(o1[4], o1[5], o1[6], o1[7]);
}

// ---------------- attention fallback (atomics) if ws too small ----------
__global__ __launch_bounds__(512) void kattn_atomic(const short* __restrict__ khvh,
                                                    const float* __restrict__ qh,
                                                    float* __restrict__ oacc,
                                                    float* __restrict__ esum) {
  __shared__ short kv[128 * 128];
  const int t = threadIdx.x;
  const int hh = t >> 6;
  const int ms = t & 63;
  {
    const int4* src = (const int4*)(khvh + (size_t)blockIdx.x * 16384);
    int4* d = (int4*)kv;
#pragma unroll
    for (int c = 0; c < 4; ++c) d[t + c * 512] = src[t + c * 512];
  }
  __syncthreads();
  float q[8][8], o[8][8], es[8];
#pragma unroll
  for (int i = 0; i < 8; ++i) {
    const float4* qp = (const float4*)(qh + ((size_t)(ms + i * 64)) * 64 + hh * 8);
    float4 q0 = qp[0], q1 = qp[1];
    q[i][0] = q0.x; q[i][1] = q0.y; q[i][2] = q0.z; q[i][3] = q0.w;
    q[i][4] = q1.x; q[i][5] = q1.y; q[i][6] = q1.z; q[i][7] = q1.w;
    es[i] = 0.f;
#pragma unroll
    for (int d = 0; d < 8; ++d) o[i][d] = 0.f;
  }
  for (int n = 0; n < 128; ++n) {
    const short8 kraw = *(const short8*)(kv + n * 128 + hh * 8);
    const short8 vraw = *(const short8*)(kv + n * 128 + 64 + hh * 8);
    float kf[8], vf[8];
#pragma unroll
    for (int d = 0; d < 8; ++d) {
      kf[d] = bf2f((ushort_t)kraw[d]);
      vf[d] = bf2f((ushort_t)vraw[d]);
    }
#pragma unroll
    for (int i = 0; i < 8; ++i) {
      float s = 0.f;
#pragma unroll
      for (int d = 0; d < 8; ++d) s = fmaf(q[i][d], kf[d], s);
      float p = __expf(s);
      es[i] += p;
#pragma unroll
      for (int d = 0; d < 8; ++d) o[i][d] = fmaf(p, vf[d], o[i][d]);
    }
  }
#pragma unroll
  for (int i = 0; i < 8; ++i) {
    const int m = ms + i * 64;
    atomicAdd(&esum[hh * 512 + m], es[i]);
#pragma unroll
    for (int d = 0; d < 8; ++d) atomicAdd(&oacc[((size_t)(hh * 512 + m)) * 8 + d], o[i][d]);
  }
}

// ---------------- fused chunk-reduce + ratio + final (main path) ----------
__global__ __launch_bounds__(256) void kfr2(const float* __restrict__ pO,
                                            const float* __restrict__ pE,
                                            const float* __restrict__ out_w,
                                            const float* __restrict__ out_b,
                                            const float* __restrict__ avg,
                                            const float* __restrict__ mem_w,
                                            float* __restrict__ out1) {
  __shared__ float ored[64];
  __shared__ float ered[8];
  __shared__ float rat[64];
  const int t = threadIdx.x;
  const int m = blockIdx.x;           // 512 blocks, one per memory slot
  if (t < 64) {
    int h = t >> 3, d = t & 7;
    float s = 0.f;
#pragma unroll 8
    for (int c = 0; c < NCH; ++c)
      s += pO[(size_t)c * 32768 + ((size_t)(h * 512 + m)) * 8 + d];
    ored[t] = s;
  } else if (t < 72) {
    int h = t - 64;
    float s = 0.f;
#pragma unroll 8
    for (int c = 0; c < NCH; ++c)
      s += pE[(size_t)c * 4096 + h * 512 + m];
    ered[h] = s;
  }
  __syncthreads();
  if (t < 64) {
    const int e = t;
    float inv[8];
#pragma unroll
    for (int h = 0; h < 8; ++h) inv[h] = 1.f / ered[h];
    float a = out_b[e];
    const float* wr = out_w + (size_t)e * 64;
#pragma unroll
    for (int j = 0; j < 64; ++j) a = fmaf(ored[j] * inv[j >> 3], wr[j], a);
    rat[e] = 1.f + a / avg[m * 64 + e];
  }
  __syncthreads();
  const float4* src = (const float4*)(mem_w + (size_t)m * 4096);
  float4* dst = (float4*)(out1 + (size_t)m * 4096);
#pragma unroll
  for (int c = 0; c < 4; ++c) {
    int idx = t + c * 256;            // 1024 float4 per m
    float rr = rat[idx >> 4];
    float4 w = src[idx];
    dst[idx] = make_float4(w.x * rr, w.y * rr, w.z * rr, w.w * rr);
  }
}

// ---------------- ratio + final from oacc/esum (fallback path) ------------
__global__ __launch_bounds__(256) void kfr(const float* __restrict__ oacc,
                                           const float* __restrict__ esum,
                                           const float* __restrict__ out_w,
                                           const float* __restrict__ out_b,
                                           const float* __restrict__ avg,
                                           const float* __restrict__ mem_w,
                                           float* __restrict__ out1) {
  __shared__ float rat[64];
  const int t = threadIdx.x;
  const int m = blockIdx.x;
  if (t < 64) {
    const int e = t;
    float of[64];
#pragma unroll
    for (int h = 0; h < 8; ++h) {
      float inv = 1.f / esum[h * 512 + m];
      const float* op = oacc + ((size_t)(h * 512 + m)) * 8;
#pragma unroll
      for (int d = 0; d < 8; ++d) of[h * 8 + d] = op[d] * inv;
    }
    float a = out_b[e];
    const float* wr = out_w + (size_t)e * 64;
#pragma unroll 8
    for (int j = 0; j < 64; ++j) a = fmaf(of[j], wr[j], a);
    rat[e] = 1.f + a / avg[m * 64 + e];
  }
  __syncthreads();
  const float4* src = (const float4*)(mem_w + (size_t)m * 4096);
  float4* dst = (float4*)(out1 + (size_t)m * 4096);
#pragma unroll
  for (int c = 0; c < 4; ++c) {
    int idx = t + c * 256;
    float rr = rat[idx >> 4];
    float4 w = src[idx];
    dst[idx] = make_float4(w.x * rr, w.y * rr, w.z * rr, w.w * rr);
  }
}

extern "C" void kernel_launch(void* const* d_in, const int* in_sizes, int n_in,
                              void* d_out, int out_size, void* d_ws, size_t ws_size,
                              hipStream_t stream) {
  (void)in_sizes; (void)n_in; (void)out_size;
  const float* x         = (const float*)d_in[0];
  const float* mem_w     = (const float*)d_in[1];
  const float* ln_g      = (const float*)d_in[2];
  const float* ln_b      = (const float*)d_in[3];
  const float* Wq        = (const float*)d_in[4];
  const float* bq        = (const float*)d_in[5];
  const float* Wk        = (const float*)d_in[6];
  const float* bk        = (const float*)d_in[7];
  const float* Wv        = (const float*)d_in[8];
  const float* bv        = (const float*)d_in[9];
  const float* in_proj_w = (const float*)d_in[10];
  const float* in_proj_b = (const float*)d_in[11];
  const float* out_w     = (const float*)d_in[12];
  const float* out_b     = (const float*)d_in[13];

  float* dout = (float*)d_out;
  char* ws = (char*)d_ws;
  short* wbf   = (short*)(ws + WBF_OFF);
  short* khvh  = (short*)(ws + KVH_OFF);
  float* qh    = (float*)(ws + QH_OFF);
  float* avg   = (float*)(ws + AVG_OFF);
  float* weff  = (float*)(ws + WEFF_OFF);
  float* beff  = (float*)(ws + BEFF_OFF);
  float* oacc  = (float*)(ws + OACC_OFF);
  float* esum  = (float*)(ws + ESUM_OFF);
  int*   flag  = (int*)(ws + FLAG_OFF);
  float* pO    = (float*)(ws + PO_OFF);
  float* pE    = (float*)(ws + PE_OFF);

  float* mem_out = dout;              // output 0: (32768, 64)
  float* out1    = dout + 2097152;    // output 1: (512, 64, 64)

  const bool use_part = (ws_size >= WS_NEED);   // host-constant: graph-safe

  hipMemsetAsync(flag, 0, 4, stream);
  kpre<<<305, 256, 0, stream>>>(mem_w, ln_g, ln_b, in_proj_w, in_proj_b,
                                Wq, bq, Wk, bk, Wv, bv, wbf, avg, weff, beff, flag);
  kqh<<<128, 256, 0, stream>>>(avg, weff, beff, qh);
  kscan<<<256, 512, 0, stream>>>(x, wbf, ln_g, ln_b, flag, mem_out);
  kkv<<<256, 256, 0, stream>>>(mem_out, weff, beff, khvh);
  if (use_part) {
    kattn2<<<NCH * 4, 512, 0, stream>>>(khvh, qh, pO, pE);
    kfr2<<<512, 256, 0, stream>>>(pO, pE, out_w, out_b, avg, mem_w, out1);
  } else {
    kinit<<<144, 256, 0, stream>>>(oacc);
    kattn_atomic<<<256, 512, 0, stream>>>(khvh, qh, oacc, esum);
    kfr<<<512, 256, 0, stream>>>(oacc, esum, out_w, out_b, avg, mem_w, out1);
  }
}

// Round 10
// 478.434 us; speedup vs baseline: 1.3132x; 1.1589x over previous
//
#include <hip/hip_runtime.h>
#include <hip/hip_bf16.h>
#include <cstdint>
#include <cstddef>

typedef __attribute__((ext_vector_type(8))) short short8;
typedef __attribute__((ext_vector_type(4))) float f32x4;
typedef __attribute__((ext_vector_type(2))) float f32x2;
typedef unsigned short ushort_t;

// ---------------- ws layout (bytes) ----------------
#define WBF_OFF   0u            // 512*64*64 bf16 (linear) = 4 MiB
#define KVH_OFF   4194304u      // 32768*128 bf16 (kh|vh per row) = 8 MiB
#define QH_OFF    12582912u     // 512*64 f32 (pre-scaled by 1/sqrt(8))
#define AVG_OFF   12713984u     // 512*64 f32 row means of mem_w
#define WEFF_OFF  12845056u     // 3 * 64*64 f32 combined projections
#define BEFF_OFF  12894208u     // 3 * 64 f32 combined biases
#define OACC_OFF  12894976u     // 8*512*8 f32 attention numerator (fallback)
#define ESUM_OFF  13026048u     // 8*512 f32 softmax denominator (fallback)
#define FLAG_OFF  13173504u     // int: nontrivial ln_g/ln_b flag
#define PO_OFF    13180928u     // 64 chunks * 32768 f32 partial O = 8 MiB
#define PE_OFF    21569536u     // 64 chunks * 4096 f32 partial esum = 1 MiB
#define WKV_OFF   22618112u     // 2 * 64*64 bf16 K/V effective mats = 16 KiB
#define WS_NEED   22634496ull   // bytes required for the main scheme
#define NCH 64                  // key chunks (512 keys each)

__device__ __forceinline__ float bf2f(ushort_t u) {
  union { unsigned int i; float f; } c; c.i = ((unsigned int)u) << 16; return c.f;
}
// Single-instruction packed f32->bf16 (RNE). No builtin on gfx950 (T12): inline asm.
__device__ __forceinline__ unsigned cvtpk(float a, float b) {
  unsigned r;
  asm("v_cvt_pk_bf16_f32 %0, %1, %2" : "=v"(r) : "v"(a), "v"(b));
  return r;
}
__device__ __forceinline__ ushort_t f2bf1(float f) {
  union { float f; unsigned int i; } c; c.f = f;
  unsigned int x = c.i;
  x += 0x7FFFu + ((x >> 16) & 1u);
  return (ushort_t)(x >> 16);
}
__device__ __forceinline__ float fbits(unsigned u) { return __builtin_bit_cast(float, u); }
__device__ __forceinline__ unsigned ubits(float f) { return __builtin_bit_cast(unsigned, f); }

// CDNA packed f32 (VOP3P, 2 f32 per instruction) — proven in R6.
__device__ __forceinline__ f32x2 pk_add(f32x2 a, f32x2 b) {
  f32x2 d; asm("v_pk_add_f32 %0, %1, %2" : "=v"(d) : "v"(a), "v"(b)); return d;
}
__device__ __forceinline__ f32x2 pk_mul(f32x2 a, f32x2 b) {
  f32x2 d; asm("v_pk_mul_f32 %0, %1, %2" : "=v"(d) : "v"(a), "v"(b)); return d;
}
__device__ __forceinline__ f32x2 pk_fma(f32x2 a, f32x2 b, f32x2 c) {
  f32x2 d; asm("v_pk_fma_f32 %0, %1, %2, %3" : "=v"(d) : "v"(a), "v"(b), "v"(c)); return d;
}

// Raw gfx950 register-pair lane swaps (in-place on both operands).
__device__ __forceinline__ void pl16raw(unsigned &a, unsigned &b) {
  asm("v_permlane16_swap_b32 %0, %1" : "+v"(a), "+v"(b));
}
__device__ __forceinline__ void pl32raw(unsigned &a, unsigned &b) {
  asm("v_permlane32_swap_b32 %0, %1" : "+v"(a), "+v"(b));
}
__device__ __forceinline__ void pl16raw_ec(unsigned &a, unsigned &b) {
  asm("v_permlane16_swap_b32 %0, %1" : "+&v"(a), "+&v"(b));
}
__device__ __forceinline__ void pl32raw_ec(unsigned &a, unsigned &b) {
  asm("v_permlane32_swap_b32 %0, %1" : "+&v"(a), "+&v"(b));
}
template<bool REV> __device__ __forceinline__ void x16(unsigned &a, unsigned &b) {
  if (!REV) pl16raw(a, b); else pl16raw(b, a);
}
template<bool REV> __device__ __forceinline__ void x32(unsigned &a, unsigned &b) {
  if (!REV) pl32raw(a, b); else pl32raw(b, a);
}
// Sum over the 4-lane group {c, c+16, c+32, c+48}; direction-agnostic.
// The asm("":"+v") copy-force is REQUIRED (R8 regression: operand coalescing
// -> v_permlane16_swap R,R self-swap -> garbage).
__device__ __forceinline__ float red4(float v) {
  unsigned a = ubits(v), b = a;
  asm("" : "+v"(b));
  pl16raw_ec(a, b);
  float w = fbits(a) + fbits(b);
  unsigned c = ubits(w), d = c;
  asm("" : "+v"(d));
  pl32raw_ec(c, d);
  return fbits(c) + fbits(d);
}

// ---------------- init (fallback only): zero accumulators ----------------
__global__ __launch_bounds__(256) void kinit(float* oacc) {
  int gid = blockIdx.x * 256 + threadIdx.x;
  if (gid < 36864) oacc[gid] = 0.f;
}

// ---------------- fused preamble: flag + prep + weff/beff + wkv bf16 ------
__global__ __launch_bounds__(256) void kpre(const float* __restrict__ mem_w,
                                            const float* __restrict__ ln_g,
                                            const float* __restrict__ ln_b,
                                            const float* __restrict__ in_proj_w,
                                            const float* __restrict__ in_proj_b,
                                            const float* __restrict__ Wq, const float* __restrict__ bq,
                                            const float* __restrict__ Wk, const float* __restrict__ bk,
                                            const float* __restrict__ Wv, const float* __restrict__ bv,
                                            short* __restrict__ wbf,
                                            float* __restrict__ avg,
                                            float* __restrict__ weff,
                                            float* __restrict__ beff,
                                            short* __restrict__ wkv,
                                            int* __restrict__ flag) {
  int gid = blockIdx.x * 256 + threadIdx.x;
  if (gid < 32768) {
    const float4* src = (const float4*)(mem_w + (size_t)gid * 64);
    int4* dst = (int4*)(wbf + (size_t)gid * 64);
    float sum = 0.f;
#pragma unroll
    for (int c = 0; c < 8; ++c) {
      float4 f0 = src[c * 2], f1 = src[c * 2 + 1];
      sum += f0.x + f0.y + f0.z + f0.w + f1.x + f1.y + f1.z + f1.w;
      int4 pk;
      pk.x = (int)cvtpk(f0.x, f0.y); pk.y = (int)cvtpk(f0.z, f0.w);
      pk.z = (int)cvtpk(f1.x, f1.y); pk.w = (int)cvtpk(f1.z, f1.w);
      dst[c] = pk;
    }
    avg[gid] = sum * 0.015625f;
  } else if (gid < 65536) {
    int j = gid - 32768;
    if (ln_g[j] != 1.0f || ln_b[j] != 0.0f) atomicOr(flag, 1);
  } else if (gid < 77824) {
    int k = gid - 65536;
    int mat = k >> 12, j = (k >> 6) & 63, e = k & 63;
    const float* Wi = in_proj_w + ((size_t)(mat * 64 + j)) * 64;
    const float* Wx = (mat == 0) ? Wq : ((mat == 1) ? Wk : Wv);
    float acc = 0.f;
#pragma unroll 8
    for (int tt = 0; tt < 64; ++tt) acc = fmaf(Wi[tt], Wx[tt * 64 + e], acc);
    weff[k] = acc;
    if (mat >= 1) wkv[(mat - 1) * 4096 + (k & 4095)] = (short)f2bf1(acc);
  } else if (gid < 78016) {
    int k = gid - 77824; int mat = k >> 6, j = k & 63;
    const float* Wi = in_proj_w + ((size_t)(mat * 64 + j)) * 64;
    const float* bx = (mat == 0) ? bq : ((mat == 1) ? bk : bv);
    float acc = in_proj_b[mat * 64 + j];
#pragma unroll 8
    for (int tt = 0; tt < 64; ++tt) acc = fmaf(Wi[tt], bx[tt], acc);
    beff[k] = acc;
  }
}

// ---------------- qh = avg_w @ Wq_eff^T + bq_eff, scaled 1/sqrt(DH) --------
__global__ __launch_bounds__(256) void kqh(const float* __restrict__ avg,
                                           const float* __restrict__ weff,
                                           const float* __restrict__ beff,
                                           float* __restrict__ qh) {
  int gid = blockIdx.x * 256 + threadIdx.x;
  int m = gid >> 6, j = gid & 63;
  const float* ar = avg + (size_t)m * 64;
  const float* wr = weff + (size_t)j * 64;
  float acc = beff[j];
#pragma unroll 8
  for (int e = 0; e < 64; ++e) acc = fmaf(ar[e], wr[e], acc);
  qh[gid] = acc * 0.35355339059327373f;
}

// ---------------- the sequential memory scan (register-resident h) --------
#define KSTEP(PP, WFC, WFN, GC, GN)                                            \
  {                                                                            \
    const int m = mb + PP;                                                     \
    if (m + 2 < 512) *(int4*)((char*)wlds[(PP + 2) & 3] + so0) = GC;           \
    if (m + 3 < 512) GN = ((const int4*)wbf)[(m + 3) * 512 + t];               \
    if (m + 1 < 512) {                                                         \
      const char* rb = (const char*)wlds[(PP + 1) & 3];                        \
      _Pragma("unroll")                                                        \
      for (int i = 0; i < 8; ++i) WFN[i] = *(const short8*)(rb + wrd[i]);      \
    }                                                                          \
    f32x4 acc0 = __builtin_amdgcn_mfma_f32_16x16x32_bf16(WFC[0], hf0, z4, 0, 0, 0); \
    f32x4 acc1 = __builtin_amdgcn_mfma_f32_16x16x32_bf16(WFC[2], hf0, z4, 0, 0, 0); \
    f32x4 acc2 = __builtin_amdgcn_mfma_f32_16x16x32_bf16(WFC[4], hf0, z4, 0, 0, 0); \
    f32x4 acc3 = __builtin_amdgcn_mfma_f32_16x16x32_bf16(WFC[6], hf0, z4, 0, 0, 0); \
    acc0 = __builtin_amdgcn_mfma_f32_16x16x32_bf16(WFC[1], hf1, acc0, 0, 0, 0); \
    acc1 = __builtin_amdgcn_mfma_f32_16x16x32_bf16(WFC[3], hf1, acc1, 0, 0, 0); \
    acc2 = __builtin_amdgcn_mfma_f32_16x16x32_bf16(WFC[5], hf1, acc2, 0, 0, 0); \
    acc3 = __builtin_amdgcn_mfma_f32_16x16x32_bf16(WFC[7], hf1, acc3, 0, 0, 0); \
    yp[0] = (f32x2){fmaxf(acc0[0], 0.f), fmaxf(acc0[1], 0.f)};                 \
    yp[1] = (f32x2){fmaxf(acc0[2], 0.f), fmaxf(acc0[3], 0.f)};                 \
    yp[2] = (f32x2){fmaxf(acc1[0], 0.f), fmaxf(acc1[1], 0.f)};                 \
    yp[3] = (f32x2){fmaxf(acc1[2], 0.f), fmaxf(acc1[3], 0.f)};                 \
    yp[4] = (f32x2){fmaxf(acc2[0], 0.f), fmaxf(acc2[1], 0.f)};                 \
    yp[5] = (f32x2){fmaxf(acc2[2], 0.f), fmaxf(acc2[3], 0.f)};                 \
    yp[6] = (f32x2){fmaxf(acc3[0], 0.f), fmaxf(acc3[1], 0.f)};                 \
    yp[7] = (f32x2){fmaxf(acc3[2], 0.f), fmaxf(acc3[3], 0.f)};                 \
    f32x2 sp = pk_add(pk_add(pk_add(yp[0], yp[1]), pk_add(yp[2], yp[3])),      \
                      pk_add(pk_add(yp[4], yp[5]), pk_add(yp[6], yp[7])));     \
    f32x2 qpa = pk_mul(yp[0], yp[0]);                                          \
    qpa = pk_fma(yp[1], yp[1], qpa);                                           \
    qpa = pk_fma(yp[2], yp[2], qpa);                                           \
    qpa = pk_fma(yp[3], yp[3], qpa);                                           \
    f32x2 qpb = pk_mul(yp[4], yp[4]);                                          \
    qpb = pk_fma(yp[5], yp[5], qpb);                                           \
    qpb = pk_fma(yp[6], yp[6], qpb);                                           \
    qpb = pk_fma(yp[7], yp[7], qpb);                                           \
    f32x2 qpt = pk_add(qpa, qpb);                                              \
    float s = red4(sp[0] + sp[1]);                                             \
    float sq = red4(qpt[0] + qpt[1]);                                          \
    const float mean = s * 0.015625f;                                          \
    const float var = fmaf(sq, 0.015625f, -mean * mean);                       \
    const float rs = rsqrtf(var + 1e-5f);                                      \
    const float cc = -mean * rs;                                               \
    if (gb) {                                                                  \
      _Pragma("unroll")                                                        \
      for (int mt = 0; mt < 4; ++mt) {                                         \
        float4 gg = *(const float4*)(ln_g + m * 64 + mt * 16 + lg * 4);        \
        float4 bb = *(const float4*)(ln_b + m * 64 + mt * 16 + lg * 4);        \
        yp[mt * 2][0]     = fmaf(fmaf(yp[mt * 2][0], rs, cc), gg.x, bb.x);     \
        yp[mt * 2][1]     = fmaf(fmaf(yp[mt * 2][1], rs, cc), gg.y, bb.y);     \
        yp[mt * 2 + 1][0] = fmaf(fmaf(yp[mt * 2 + 1][0], rs, cc), gg.z, bb.z); \
        yp[mt * 2 + 1][1] = fmaf(fmaf(yp[mt * 2 + 1][1], rs, cc), gg.w, bb.w); \
      }                                                                        \
    } else {                                                                   \
      const f32x2 rs2 = (f32x2){rs, rs};                                       \
      const f32x2 cc2 = (f32x2){cc, cc};                                       \
      _Pragma("unroll")                                                        \
      for (int i = 0; i < 8; ++i) yp[i] = pk_fma(yp[i], rs2, cc2);             \
    }                                                                          \
    if (m < 511) {                                                             \
      unsigned Q0 = cvtpk(yp[0][0], yp[0][1]), Q1 = cvtpk(yp[1][0], yp[1][1]); \
      unsigned Q2 = cvtpk(yp[2][0], yp[2][1]), Q3 = cvtpk(yp[3][0], yp[3][1]); \
      unsigned Q4 = cvtpk(yp[4][0], yp[4][1]), Q5 = cvtpk(yp[5][0], yp[5][1]); \
      unsigned Q6 = cvtpk(yp[6][0], yp[6][1]), Q7 = cvtpk(yp[7][0], yp[7][1]); \
      x32<R32>(Q0, Q2); x16<R16>(Q0, Q2);                                      \
      x32<R32>(Q1, Q3); x16<R16>(Q1, Q3);                                      \
      x32<R32>(Q4, Q6); x16<R16>(Q4, Q6);                                      \
      x32<R32>(Q5, Q7); x16<R16>(Q5, Q7);                                      \
      union { unsigned d[4]; short8 s8; } uu0, uu1;                            \
      uu0.d[0] = Q0; uu0.d[1] = Q1; uu0.d[2] = Q2; uu0.d[3] = Q3;              \
      uu1.d[0] = Q4; uu1.d[1] = Q5; uu1.d[2] = Q6; uu1.d[3] = Q7;              \
      hf0 = uu0.s8; hf1 = uu1.s8;                                              \
    }                                                                          \
    asm volatile("s_waitcnt lgkmcnt(8)" ::: "memory");                         \
    __builtin_amdgcn_s_barrier();                                              \
  }

template<bool R16, bool R32>
__device__ void kscan_body(const float* __restrict__ x,
                           const short* __restrict__ wbf,
                           const float* __restrict__ ln_g,
                           const float* __restrict__ ln_b,
                           int gb, float* __restrict__ mem_out,
                           short* __restrict__ wldsb) {
  short (*wlds)[64 * 64] = (short (*)[64 * 64])wldsb;
  const int t = threadIdx.x;
  const int lane = t & 63;
  const int wv = t >> 6;
  const int lcol = lane & 15;
  const int lg = lane >> 4;
  const int blk = blockIdx.x;
  const int r = wv * 16 + lcol;

  const int wsw = (lcol & 7) << 4;
  int wrd[8];
#pragma unroll
  for (int mt = 0; mt < 4; ++mt) {
    wrd[mt * 2]     = mt * 2048 + lcol * 128 + ((lg * 16) ^ wsw);
    wrd[mt * 2 + 1] = mt * 2048 + lcol * 128 + ((lg * 16 + 64) ^ wsw);
  }
  const int so0 = (t * 16) ^ ((((t * 16) >> 7) & 7) << 4);

  short8 hf0, hf1;
  {
    const float4* xr = (const float4*)(x + ((size_t)(blk * 128 + r)) * 64);
    float4 a0 = xr[lg * 2], a1 = xr[lg * 2 + 1];
    float4 b0 = xr[8 + lg * 2], b1 = xr[8 + lg * 2 + 1];
    union { unsigned d[4]; short8 s8; } u0, u1;
    u0.d[0] = cvtpk(a0.x, a0.y); u0.d[1] = cvtpk(a0.z, a0.w);
    u0.d[2] = cvtpk(a1.x, a1.y); u0.d[3] = cvtpk(a1.z, a1.w);
    u1.d[0] = cvtpk(b0.x, b0.y); u1.d[1] = cvtpk(b0.z, b0.w);
    u1.d[2] = cvtpk(b1.x, b1.y); u1.d[3] = cvtpk(b1.z, b1.w);
    hf0 = u0.s8; hf1 = u1.s8;
  }
  {
    int4 w0 = ((const int4*)wbf)[t];
    int4 w1 = ((const int4*)wbf)[512 + t];
    *(int4*)((char*)wlds[0] + so0) = w0;
    *(int4*)((char*)wlds[1] + so0) = w1;
  }
  int4 g0 = ((const int4*)wbf)[1024 + t];
  int4 g1;
  __syncthreads();

  short8 wfA[8], wfB[8];
#pragma unroll
  for (int i = 0; i < 8; ++i) wfA[i] = *(const short8*)((const char*)wlds[0] + wrd[i]);

  const f32x4 z4 = {0.f, 0.f, 0.f, 0.f};
  f32x2 yp[8];

  for (int mb = 0; mb < 512; mb += 4) {
    KSTEP(0, wfA, wfB, g0, g1)
    KSTEP(1, wfB, wfA, g1, g0)
    KSTEP(2, wfA, wfB, g0, g1)
    KSTEP(3, wfB, wfA, g1, g0)
  }

  float* mo = mem_out + ((size_t)(blk * 128 + r)) * 64;
#pragma unroll
  for (int mt = 0; mt < 4; ++mt)
    *(float4*)(mo + mt * 16 + lg * 4) =
        make_float4(yp[mt * 2][0], yp[mt * 2][1], yp[mt * 2 + 1][0], yp[mt * 2 + 1][1]);
}

__global__ __launch_bounds__(512, 2) void kscan(
    const float* __restrict__ x, const short* __restrict__ wbf,
    const float* __restrict__ ln_g, const float* __restrict__ ln_b,
    const int* __restrict__ flagp, float* __restrict__ mem_out) {
  __shared__ short wlds[4][64 * 64];
  const int lane = threadIdx.x & 63;
  const int gb = *flagp;
  unsigned pa = (unsigned)lane, pb = 1000u + (unsigned)lane;
  pl16raw_ec(pa, pb);
  const bool r16 = (__builtin_amdgcn_readfirstlane((int)pa) != 0);
  unsigned qa = (unsigned)lane, qb = 2000u + (unsigned)lane;
  pl32raw_ec(qa, qb);
  const bool r32 = (__builtin_amdgcn_readfirstlane((int)qa) != 0);
  short* ldsb = &wlds[0][0];
  if (!r16) {
    if (!r32) kscan_body<false, false>(x, wbf, ln_g, ln_b, gb, mem_out, ldsb);
    else      kscan_body<false, true >(x, wbf, ln_g, ln_b, gb, mem_out, ldsb);
  } else {
    if (!r32) kscan_body<true, false >(x, wbf, ln_g, ln_b, gb, mem_out, ldsb);
    else      kscan_body<true, true  >(x, wbf, ln_g, ln_b, gb, mem_out, ldsb);
  }
}

// ---------------- kh/vh via MFMA (main path) ------------------------------
// 256 blocks x 512 thr; 128 rows/block, wave = 16 rows, 16 MFMA/wave.
__global__ __launch_bounds__(512) void kkvm(const float* __restrict__ mem_out,
                                            const short* __restrict__ wkv,
                                            const float* __restrict__ beff,
                                            short* __restrict__ khvh) {
  __shared__ short wl[2][64 * 64];
  const int t = threadIdx.x;
  const int lane = t & 63;
  const int wv = t >> 6;
  const int lcol = lane & 15;
  const int lg = lane >> 4;
  const int r = wv * 16 + lcol;
  const int n = blockIdx.x * 128 + r;
  const int wsw = (lcol & 7) << 4;
  int wrd[8];
#pragma unroll
  for (int mt = 0; mt < 4; ++mt) {
    wrd[mt * 2]     = mt * 2048 + lcol * 128 + ((lg * 16) ^ wsw);
    wrd[mt * 2 + 1] = mt * 2048 + lcol * 128 + ((lg * 16 + 64) ^ wsw);
  }
  const int so0 = (t * 16) ^ ((((t * 16) >> 7) & 7) << 4);
  {
    const int4* wp = (const int4*)wkv;
    *(int4*)((char*)wl[0] + so0) = wp[t];          // K-mat (8 KiB)
    *(int4*)((char*)wl[1] + so0) = wp[512 + t];    // V-mat (8 KiB)
  }
  short8 hf0, hf1;
  {
    const float4* xr = (const float4*)(mem_out + (size_t)n * 64);
    float4 a0 = xr[lg * 2], a1 = xr[lg * 2 + 1];
    float4 b0 = xr[8 + lg * 2], b1 = xr[8 + lg * 2 + 1];
    union { unsigned d[4]; short8 s8; } u0, u1;
    u0.d[0] = cvtpk(a0.x, a0.y); u0.d[1] = cvtpk(a0.z, a0.w);
    u0.d[2] = cvtpk(a1.x, a1.y); u0.d[3] = cvtpk(a1.z, a1.w);
    u1.d[0] = cvtpk(b0.x, b0.y); u1.d[1] = cvtpk(b0.z, b0.w);
    u1.d[2] = cvtpk(b1.x, b1.y); u1.d[3] = cvtpk(b1.z, b1.w);
    hf0 = u0.s8; hf1 = u1.s8;
  }
  __syncthreads();
  const f32x4 z4 = {0.f, 0.f, 0.f, 0.f};
  short* row = khvh + (size_t)n * 128;
#pragma unroll
  for (int mt = 0; mt < 4; ++mt) {
    short8 k0 = *(const short8*)((const char*)wl[0] + wrd[mt * 2]);
    short8 k1 = *(const short8*)((const char*)wl[0] + wrd[mt * 2 + 1]);
    f32x4 aK = __builtin_amdgcn_mfma_f32_16x16x32_bf16(k0, hf0, z4, 0, 0, 0);
    aK = __builtin_amdgcn_mfma_f32_16x16x32_bf16(k1, hf1, aK, 0, 0, 0);
    short8 v0 = *(const short8*)((const char*)wl[1] + wrd[mt * 2]);
    short8 v1 = *(const short8*)((const char*)wl[1] + wrd[mt * 2 + 1]);
    f32x4 aV = __builtin_amdgcn_mfma_f32_16x16x32_bf16(v0, hf0, z4, 0, 0, 0);
    aV = __builtin_amdgcn_mfma_f32_16x16x32_bf16(v1, hf1, aV, 0, 0, 0);
    float4 bk = *(const float4*)(beff + 64 + mt * 16 + lg * 4);
    float4 bv = *(const float4*)(beff + 128 + mt * 16 + lg * 4);
    uint2 pk_, pv_;
    pk_.x = cvtpk(aK[0] + bk.x, aK[1] + bk.y);
    pk_.y = cvtpk(aK[2] + bk.z, aK[3] + bk.w);
    pv_.x = cvtpk(aV[0] + bv.x, aV[1] + bv.y);
    pv_.y = cvtpk(aV[2] + bv.z, aV[3] + bv.w);
    *(uint2*)(row + mt * 16 + lg * 4) = pk_;
    *(uint2*)(row + 64 + mt * 16 + lg * 4) = pv_;
  }
}

// ---------------- kh/vh scalar (fallback path only) -----------------------
__global__ __launch_bounds__(256) void kkv(const float* __restrict__ mem_out,
                                           const float* __restrict__ weff,
                                           const float* __restrict__ beff,
                                           short* __restrict__ khvh) {
  __shared__ short kvs[128 * 128];
  const int t = threadIdx.x;
  const int nl = t >> 1;
  const int jh = (t & 1) * 32;
  const int n = blockIdx.x * 128 + nl;
  float mo[64];
  const float4* mop = (const float4*)(mem_out + (size_t)n * 64);
#pragma unroll
  for (int c = 0; c < 16; ++c) {
    float4 f = mop[c];
    mo[c * 4] = f.x; mo[c * 4 + 1] = f.y; mo[c * 4 + 2] = f.z; mo[c * 4 + 3] = f.w;
  }
  const float* wk = weff + 4096;
  const float* wvp = weff + 8192;
  const float* bk = beff + 64;
  const float* bv = beff + 128;
  for (int jj = 0; jj < 32; ++jj) {
    const int j = jh + jj;
    float ak = bk[j], av = bv[j];
    const float* wkr = wk + (size_t)j * 64;
    const float* wvr = wvp + (size_t)j * 64;
#pragma unroll 8
    for (int e = 0; e < 64; ++e) { ak = fmaf(mo[e], wkr[e], ak); av = fmaf(mo[e], wvr[e], av); }
    kvs[nl * 128 + j] = (short)f2bf1(ak);
    kvs[nl * 128 + 64 + j] = (short)f2bf1(av);
  }
  __syncthreads();
  int4* dst = (int4*)(khvh + (size_t)blockIdx.x * 16384);
  const int4* srcl = (const int4*)kvs;
#pragma unroll
  for (int c = 0; c < 8; ++c) dst[t + c * 256] = srcl[t + c * 256];
}

// ---------------- attention, two-stage, bf16 LDS tiles --------------------
// (R3-proven inner loop: 2 ds_read_b128/key, convert in-register.)
__global__ __launch_bounds__(512) void kattn2(const short* __restrict__ khvh,
                                              const float* __restrict__ qh,
                                              float* __restrict__ pO,
                                              float* __restrict__ pE) {
  __shared__ short kv[128 * 128];   // 128-key tile (K|V rows), 32 KiB
  const int t = threadIdx.x;
  const int hh = t >> 6;
  const int ml = t & 63;
  const int c = blockIdx.x >> 2;
  const int mc = blockIdx.x & 3;
  const int m0 = mc * 128 + ml;
  const int m1 = m0 + 64;
  float q0[8], q1[8], o0[8], o1[8];
  float e0 = 0.f, e1 = 0.f;
  {
    const float4* qp0 = (const float4*)(qh + (size_t)m0 * 64 + hh * 8);
    const float4* qp1 = (const float4*)(qh + (size_t)m1 * 64 + hh * 8);
    float4 a = qp0[0], b = qp0[1], cc2 = qp1[0], d2 = qp1[1];
    q0[0]=a.x; q0[1]=a.y; q0[2]=a.z; q0[3]=a.w; q0[4]=b.x; q0[5]=b.y; q0[6]=b.z; q0[7]=b.w;
    q1[0]=cc2.x; q1[1]=cc2.y; q1[2]=cc2.z; q1[3]=cc2.w; q1[4]=d2.x; q1[5]=d2.y; q1[6]=d2.z; q1[7]=d2.w;
#pragma unroll
    for (int d = 0; d < 8; ++d) { o0[d] = 0.f; o1[d] = 0.f; }
  }
  for (int tile = 0; tile < 4; ++tile) {
    if (tile) __syncthreads();
    const int4* src = (const int4*)(khvh + ((size_t)(c * 512 + tile * 128)) * 128);
    int4* dl = (int4*)kv;
#pragma unroll
    for (int u = 0; u < 4; ++u) dl[t + u * 512] = src[t + u * 512];
    __syncthreads();
    for (int n = 0; n < 128; ++n) {
      const short8 kraw = *(const short8*)(kv + n * 128 + hh * 8);
      const short8 vraw = *(const short8*)(kv + n * 128 + 64 + hh * 8);
      float kf[8], vf[8];
#pragma unroll
      for (int d = 0; d < 8; ++d) {
        kf[d] = bf2f((ushort_t)kraw[d]);
        vf[d] = bf2f((ushort_t)vraw[d]);
      }
      float s0 = 0.f, s1 = 0.f;
#pragma unroll
      for (int d = 0; d < 8; ++d) { s0 = fmaf(q0[d], kf[d], s0); s1 = fmaf(q1[d], kf[d], s1); }
      float p0 = __expf(s0), p1 = __expf(s1);
      e0 += p0; e1 += p1;
#pragma unroll
      for (int d = 0; d < 8; ++d) { o0[d] = fmaf(p0, vf[d], o0[d]); o1[d] = fmaf(p1, vf[d], o1[d]); }
    }
  }
  const int idx0 = hh * 512 + m0;
  const int idx1 = hh * 512 + m1;
  pE[(size_t)c * 4096 + idx0] = e0;
  pE[(size_t)c * 4096 + idx1] = e1;
  float4* po0 = (float4*)(pO + (size_t)c * 32768 + (size_t)idx0 * 8);
  float4* po1 = (float4*)(pO + (size_t)c * 32768 + (size_t)idx1 * 8);
  po0[0] = make_float4(o0[0], o0[1], o0[2], o0[3]);
  po0[1] = make_float4(o0[4], o0[5], o0[6], o0[7]);
  po1[0] = make_float4(o1[0], o1[1], o1[2], o1[3]);
  po1[1] = make_float4(o1[4], o1[5], o1[6], o1[7]);
}

// ---------------- attention fallback (atomics) if ws too small ----------
__global__ __launch_bounds__(512) void kattn_atomic(const short* __restrict__ khvh,
                                                    const float* __restrict__ qh,
                                                    float* __restrict__ oacc,
                                                    float* __restrict__ esum) {
  __shared__ short kv[128 * 128];
  const int t = threadIdx.x;
  const int hh = t >> 6;
  const int ms = t & 63;
  {
    const int4* src = (const int4*)(khvh + (size_t)blockIdx.x * 16384);
    int4* d = (int4*)kv;
#pragma unroll
    for (int c = 0; c < 4; ++c) d[t + c * 512] = src[t + c * 512];
  }
  __syncthreads();
  float q[8][8], o[8][8], es[8];
#pragma unroll
  for (int i = 0; i < 8; ++i) {
    const float4* qp = (const float4*)(qh + ((size_t)(ms + i * 64)) * 64 + hh * 8);
    float4 q0 = qp[0], q1 = qp[1];
    q[i][0] = q0.x; q[i][1] = q0.y; q[i][2] = q0.z; q[i][3] = q0.w;
    q[i][4] = q1.x; q[i][5] = q1.y; q[i][6] = q1.z; q[i][7] = q1.w;
    es[i] = 0.f;
#pragma unroll
    for (int d = 0; d < 8; ++d) o[i][d] = 0.f;
  }
  for (int n = 0; n < 128; ++n) {
    const short8 kraw = *(const short8*)(kv + n * 128 + hh * 8);
    const short8 vraw = *(const short8*)(kv + n * 128 + 64 + hh * 8);
    float kf[8], vf[8];
#pragma unroll
    for (int d = 0; d < 8; ++d) {
      kf[d] = bf2f((ushort_t)kraw[d]);
      vf[d] = bf2f((ushort_t)vraw[d]);
    }
#pragma unroll
    for (int i = 0; i < 8; ++i) {
      float s = 0.f;
#pragma unroll
      for (int d = 0; d < 8; ++d) s = fmaf(q[i][d], kf[d], s);
      float p = __expf(s);
      es[i] += p;
#pragma unroll
      for (int d = 0; d < 8; ++d) o[i][d] = fmaf(p, vf[d], o[i][d]);
    }
  }
#pragma unroll
  for (int i = 0; i < 8; ++i) {
    const int m = ms + i * 64;
    atomicAdd(&esum[hh * 512 + m], es[i]);
#pragma unroll
    for (int d = 0; d < 8; ++d) atomicAdd(&oacc[((size_t)(hh * 512 + m)) * 8 + d], o[i][d]);
  }
}

// ---------------- fused chunk-reduce + ratio + final (main path) ----------
__global__ __launch_bounds__(256) void kfr2(const float* __restrict__ pO,
                                            const float* __restrict__ pE,
                                            const float* __restrict__ out_w,
                                            const float* __restrict__ out_b,
                                            const float* __restrict__ avg,
                                            const float* __restrict__ mem_w,
                                            float* __restrict__ out1) {
  __shared__ float ored[64];
  __shared__ float ered[8];
  __shared__ float rat[64];
  const int t = threadIdx.x;
  const int m = blockIdx.x;
  if (t < 64) {
    int h = t >> 3, d = t & 7;
    float s = 0.f;
#pragma unroll 8
    for (int c = 0; c < NCH; ++c)
      s += pO[(size_t)c * 32768 + ((size_t)(h * 512 + m)) * 8 + d];
    ored[t] = s;
  } else if (t < 72) {
    int h = t - 64;
    float s = 0.f;
#pragma unroll 8
    for (int c = 0; c < NCH; ++c)
      s += pE[(size_t)c * 4096 + h * 512 + m];
    ered[h] = s;
  }
  __syncthreads();
  if (t < 64) {
    const int e = t;
    float inv[8];
#pragma unroll
    for (int h = 0; h < 8; ++h) inv[h] = 1.f / ered[h];
    float a = out_b[e];
    const float* wr = out_w + (size_t)e * 64;
#pragma unroll
    for (int j = 0; j < 64; ++j) a = fmaf(ored[j] * inv[j >> 3], wr[j], a);
    rat[e] = 1.f + a / avg[m * 64 + e];
  }
  __syncthreads();
  const float4* src = (const float4*)(mem_w + (size_t)m * 4096);
  float4* dst = (float4*)(out1 + (size_t)m * 4096);
#pragma unroll
  for (int c = 0; c < 4; ++c) {
    int idx = t + c * 256;
    float rr = rat[idx >> 4];
    float4 w = src[idx];
    dst[idx] = make_float4(w.x * rr, w.y * rr, w.z * rr, w.w * rr);
  }
}

// ---------------- ratio + final from oacc/esum (fallback path) ------------
__global__ __launch_bounds__(256) void kfr(const float* __restrict__ oacc,
                                           const float* __restrict__ esum,
                                           const float* __restrict__ out_w,
                                           const float* __restrict__ out_b,
                                           const float* __restrict__ avg,
                                           const float* __restrict__ mem_w,
                                           float* __restrict__ out1) {
  __shared__ float rat[64];
  const int t = threadIdx.x;
  const int m = blockIdx.x;
  if (t < 64) {
    const int e = t;
    float of[64];
#pragma unroll
    for (int h = 0; h < 8; ++h) {
      float inv = 1.f / esum[h * 512 + m];
      const float* op = oacc + ((size_t)(h * 512 + m)) * 8;
#pragma unroll
      for (int d = 0; d < 8; ++d) of[h * 8 + d] = op[d] * inv;
    }
    float a = out_b[e];
    const float* wr = out_w + (size_t)e * 64;
#pragma unroll 8
    for (int j = 0; j < 64; ++j) a = fmaf(of[j], wr[j], a);
    rat[e] = 1.f + a / avg[m * 64 + e];
  }
  __syncthreads();
  const float4* src = (const float4*)(mem_w + (size_t)m * 4096);
  float4* dst = (float4*)(out1 + (size_t)m * 4096);
#pragma unroll
  for (int c = 0; c < 4; ++c) {
    int idx = t + c * 256;
    float rr = rat[idx >> 4];
    float4 w = src[idx];
    dst[idx] = make_float4(w.x * rr, w.y * rr, w.z * rr, w.w * rr);
  }
}

extern "C" void kernel_launch(void* const* d_in, const int* in_sizes, int n_in,
                              void* d_out, int out_size, void* d_ws, size_t ws_size,
                              hipStream_t stream) {
  (void)in_sizes; (void)n_in; (void)out_size;
  const float* x         = (const float*)d_in[0];
  const float* mem_w     = (const float*)d_in[1];
  const float* ln_g      = (const float*)d_in[2];
  const float* ln_b      = (const float*)d_in[3];
  const float* Wq        = (const float*)d_in[4];
  const float* bq        = (const float*)d_in[5];
  const float* Wk        = (const float*)d_in[6];
  const float* bk        = (const float*)d_in[7];
  const float* Wv        = (const float*)d_in[8];
  const float* bv        = (const float*)d_in[9];
  const float* in_proj_w = (const float*)d_in[10];
  const float* in_proj_b = (const float*)d_in[11];
  const float* out_w     = (const float*)d_in[12];
  const float* out_b     = (const float*)d_in[13];

  float* dout = (float*)d_out;
  char* ws = (char*)d_ws;
  short* wbf   = (short*)(ws + WBF_OFF);
  short* khvh  = (short*)(ws + KVH_OFF);
  float* qh    = (float*)(ws + QH_OFF);
  float* avg   = (float*)(ws + AVG_OFF);
  float* weff  = (float*)(ws + WEFF_OFF);
  float* beff  = (float*)(ws + BEFF_OFF);
  float* oacc  = (float*)(ws + OACC_OFF);
  float* esum  = (float*)(ws + ESUM_OFF);
  int*   flag  = (int*)(ws + FLAG_OFF);
  float* pO    = (float*)(ws + PO_OFF);
  float* pE    = (float*)(ws + PE_OFF);
  short* wkv   = (short*)(ws + WKV_OFF);

  float* mem_out = dout;              // output 0: (32768, 64)
  float* out1    = dout + 2097152;    // output 1: (512, 64, 64)

  const bool use_part = (ws_size >= WS_NEED);   // host-constant: graph-safe

  hipMemsetAsync(flag, 0, 4, stream);
  kpre<<<305, 256, 0, stream>>>(mem_w, ln_g, ln_b, in_proj_w, in_proj_b,
                                Wq, bq, Wk, bk, Wv, bv, wbf, avg, weff, beff,
                                wkv, flag);
  kqh<<<128, 256, 0, stream>>>(avg, weff, beff, qh);
  kscan<<<256, 512, 0, stream>>>(x, wbf, ln_g, ln_b, flag, mem_out);
  if (use_part) {
    kkvm<<<256, 512, 0, stream>>>(mem_out, wkv, beff, khvh);
    kattn2<<<NCH * 4, 512, 0, stream>>>(khvh, qh, pO, pE);
    kfr2<<<512, 256, 0, stream>>>(pO, pE, out_w, out_b, avg, mem_w, out1);
  } else {
    kkv<<<256, 256, 0, stream>>>(mem_out, weff, beff, khvh);
    kinit<<<144, 256, 0, stream>>>(oacc);
    kattn_atomic<<<256, 512, 0, stream>>>(khvh, qh, oacc, esum);
    kfr<<<512, 256, 0, stream>>>(oacc, esum, out_w, out_b, avg, mem_w, out1);
  }
}

// Round 11
// 465.040 us; speedup vs baseline: 1.3510x; 1.0288x over previous
//
#include <hip/hip_runtime.h>
#include <hip/hip_bf16.h>
#include <cstdint>
#include <cstddef>

typedef __attribute__((ext_vector_type(8))) short short8;
typedef __attribute__((ext_vector_type(4))) float f32x4;
typedef unsigned short ushort_t;

// ---------------- ws layout (bytes) ----------------
#define WBF_OFF   0u            // 512*64*64 bf16 (linear) = 4 MiB
#define KVH_OFF   4194304u      // 32768*128 bf16 (kh|vh per row) = 8 MiB
#define QH_OFF    12582912u     // 512*64 f32 (pre-scaled by 1/sqrt(8))
#define AVG_OFF   12713984u     // 512*64 f32 row means of mem_w
#define WEFF_OFF  12845056u     // 3 * 64*64 f32 combined projections
#define BEFF_OFF  12894208u     // 3 * 64 f32 combined biases
#define OACC_OFF  12894976u     // 8*512*8 f32 attention numerator (fallback)
#define ESUM_OFF  13026048u     // 8*512 f32 softmax denominator (fallback)
#define FLAG_OFF  13173504u     // int: nontrivial ln_g/ln_b flag
#define PO_OFF    13180928u     // 64 chunks * 32768 f32 partial O = 8 MiB
#define PE_OFF    21569536u     // 64 chunks * 4096 f32 partial esum = 1 MiB
#define WKV_OFF   22618112u     // 2 * 64*64 bf16 K/V effective mats = 16 KiB
#define WS_NEED   22634496ull   // bytes required for the main scheme
#define NCH 64                  // key chunks (512 keys each)

__device__ __forceinline__ float bf2f(ushort_t u) {
  union { unsigned int i; float f; } c; c.i = ((unsigned int)u) << 16; return c.f;
}
// Single-instruction packed f32->bf16 (RNE). No builtin on gfx950 (T12): inline asm.
__device__ __forceinline__ unsigned cvtpk(float a, float b) {
  unsigned r;
  asm("v_cvt_pk_bf16_f32 %0, %1, %2" : "=v"(r) : "v"(a), "v"(b));
  return r;
}
__device__ __forceinline__ ushort_t f2bf1(float f) {
  union { float f; unsigned int i; } c; c.f = f;
  unsigned int x = c.i;
  x += 0x7FFFu + ((x >> 16) & 1u);
  return (ushort_t)(x >> 16);
}
__device__ __forceinline__ float fbits(unsigned u) { return __builtin_bit_cast(float, u); }
__device__ __forceinline__ unsigned ubits(float f) { return __builtin_bit_cast(unsigned, f); }

// Raw gfx950 register-pair lane swaps (in-place on both operands).
__device__ __forceinline__ void pl16raw(unsigned &a, unsigned &b) {
  asm("v_permlane16_swap_b32 %0, %1" : "+v"(a), "+v"(b));
}
__device__ __forceinline__ void pl32raw(unsigned &a, unsigned &b) {
  asm("v_permlane32_swap_b32 %0, %1" : "+v"(a), "+v"(b));
}
__device__ __forceinline__ void pl16raw_ec(unsigned &a, unsigned &b) {
  asm("v_permlane16_swap_b32 %0, %1" : "+&v"(a), "+&v"(b));
}
__device__ __forceinline__ void pl32raw_ec(unsigned &a, unsigned &b) {
  asm("v_permlane32_swap_b32 %0, %1" : "+&v"(a), "+&v"(b));
}
template<bool REV> __device__ __forceinline__ void x16(unsigned &a, unsigned &b) {
  if (!REV) pl16raw(a, b); else pl16raw(b, a);
}
template<bool REV> __device__ __forceinline__ void x32(unsigned &a, unsigned &b) {
  if (!REV) pl32raw(a, b); else pl32raw(b, a);
}
// Sum over the 4-lane group {c, c+16, c+32, c+48}; direction-agnostic.
// The asm("":"+v") copy-force is REQUIRED (R8 regression: operand coalescing
// -> v_permlane16_swap R,R self-swap -> garbage).
__device__ __forceinline__ float red4(float v) {
  unsigned a = ubits(v), b = a;
  asm("" : "+v"(b));
  pl16raw_ec(a, b);
  float w = fbits(a) + fbits(b);
  unsigned c = ubits(w), d = c;
  asm("" : "+v"(d));
  pl32raw_ec(c, d);
  return fbits(c) + fbits(d);
}

// ---------------- init (fallback only): zero accumulators ----------------
__global__ __launch_bounds__(256) void kinit(float* oacc) {
  int gid = blockIdx.x * 256 + threadIdx.x;
  if (gid < 36864) oacc[gid] = 0.f;
}

// ---------------- fused preamble: flag + prep + weff/beff + wkv bf16 ------
__global__ __launch_bounds__(256) void kpre(const float* __restrict__ mem_w,
                                            const float* __restrict__ ln_g,
                                            const float* __restrict__ ln_b,
                                            const float* __restrict__ in_proj_w,
                                            const float* __restrict__ in_proj_b,
                                            const float* __restrict__ Wq, const float* __restrict__ bq,
                                            const float* __restrict__ Wk, const float* __restrict__ bk,
                                            const float* __restrict__ Wv, const float* __restrict__ bv,
                                            short* __restrict__ wbf,
                                            float* __restrict__ avg,
                                            float* __restrict__ weff,
                                            float* __restrict__ beff,
                                            short* __restrict__ wkv,
                                            int* __restrict__ flag) {
  int gid = blockIdx.x * 256 + threadIdx.x;
  if (gid < 32768) {
    const float4* src = (const float4*)(mem_w + (size_t)gid * 64);
    int4* dst = (int4*)(wbf + (size_t)gid * 64);
    float sum = 0.f;
#pragma unroll
    for (int c = 0; c < 8; ++c) {
      float4 f0 = src[c * 2], f1 = src[c * 2 + 1];
      sum += f0.x + f0.y + f0.z + f0.w + f1.x + f1.y + f1.z + f1.w;
      int4 pk;
      pk.x = (int)cvtpk(f0.x, f0.y); pk.y = (int)cvtpk(f0.z, f0.w);
      pk.z = (int)cvtpk(f1.x, f1.y); pk.w = (int)cvtpk(f1.z, f1.w);
      dst[c] = pk;
    }
    avg[gid] = sum * 0.015625f;
  } else if (gid < 65536) {
    int j = gid - 32768;
    if (ln_g[j] != 1.0f || ln_b[j] != 0.0f) atomicOr(flag, 1);
  } else if (gid < 77824) {
    int k = gid - 65536;
    int mat = k >> 12, j = (k >> 6) & 63, e = k & 63;
    const float* Wi = in_proj_w + ((size_t)(mat * 64 + j)) * 64;
    const float* Wx = (mat == 0) ? Wq : ((mat == 1) ? Wk : Wv);
    float acc = 0.f;
#pragma unroll 8
    for (int tt = 0; tt < 64; ++tt) acc = fmaf(Wi[tt], Wx[tt * 64 + e], acc);
    weff[k] = acc;
    if (mat >= 1) wkv[(mat - 1) * 4096 + (k & 4095)] = (short)f2bf1(acc);
  } else if (gid < 78016) {
    int k = gid - 77824; int mat = k >> 6, j = k & 63;
    const float* Wi = in_proj_w + ((size_t)(mat * 64 + j)) * 64;
    const float* bx = (mat == 0) ? bq : ((mat == 1) ? bk : bv);
    float acc = in_proj_b[mat * 64 + j];
#pragma unroll 8
    for (int tt = 0; tt < 64; ++tt) acc = fmaf(Wi[tt], bx[tt], acc);
    beff[k] = acc;
  }
}

// ---------------- qh = avg_w @ Wq_eff^T + bq_eff, scaled 1/sqrt(DH) --------
__global__ __launch_bounds__(256) void kqh(const float* __restrict__ avg,
                                           const float* __restrict__ weff,
                                           const float* __restrict__ beff,
                                           float* __restrict__ qh) {
  int gid = blockIdx.x * 256 + threadIdx.x;
  int m = gid >> 6, j = gid & 63;
  const float* ar = avg + (size_t)m * 64;
  const float* wr = weff + (size_t)j * 64;
  float acc = beff[j];
#pragma unroll 8
  for (int e = 0; e < 64; ++e) acc = fmaf(ar[e], wr[e], acc);
  qh[gid] = acc * 0.35355339059327373f;
}

// ---------------- the sequential memory scan (register-resident h) --------
// 512 thr (8 waves), 128 rows/block, 256 blocks. h in registers; C-frag ->
// next B-frag via v_cvt_pk_bf16_f32 + permlane swaps. W in 4-slot LDS ring;
// barrier every step; ds_write issued FIRST so lgkmcnt(8) drains only it.
// (R9-proven scalar form — pk-f32 variant regressed, R10 post-mortem.)
#define KSTEP(PP, WFC, WFN, GC, GN)                                            \
  {                                                                            \
    const int m = mb + PP;                                                     \
    if (m + 2 < 512) *(int4*)((char*)wlds[(PP + 2) & 3] + so0) = GC;           \
    if (m + 3 < 512) GN = ((const int4*)wbf)[(m + 3) * 512 + t];               \
    if (m + 1 < 512) {                                                         \
      const char* rb = (const char*)wlds[(PP + 1) & 3];                        \
      _Pragma("unroll")                                                        \
      for (int i = 0; i < 8; ++i) WFN[i] = *(const short8*)(rb + wrd[i]);      \
    }                                                                          \
    f32x4 acc0 = __builtin_amdgcn_mfma_f32_16x16x32_bf16(WFC[0], hf0, z4, 0, 0, 0); \
    f32x4 acc1 = __builtin_amdgcn_mfma_f32_16x16x32_bf16(WFC[2], hf0, z4, 0, 0, 0); \
    f32x4 acc2 = __builtin_amdgcn_mfma_f32_16x16x32_bf16(WFC[4], hf0, z4, 0, 0, 0); \
    f32x4 acc3 = __builtin_amdgcn_mfma_f32_16x16x32_bf16(WFC[6], hf0, z4, 0, 0, 0); \
    acc0 = __builtin_amdgcn_mfma_f32_16x16x32_bf16(WFC[1], hf1, acc0, 0, 0, 0); \
    acc1 = __builtin_amdgcn_mfma_f32_16x16x32_bf16(WFC[3], hf1, acc1, 0, 0, 0); \
    acc2 = __builtin_amdgcn_mfma_f32_16x16x32_bf16(WFC[5], hf1, acc2, 0, 0, 0); \
    acc3 = __builtin_amdgcn_mfma_f32_16x16x32_bf16(WFC[7], hf1, acc3, 0, 0, 0); \
    _Pragma("unroll")                                                          \
    for (int rg = 0; rg < 4; ++rg) {                                           \
      outv[rg]      = fmaxf(acc0[rg], 0.f);                                    \
      outv[4 + rg]  = fmaxf(acc1[rg], 0.f);                                    \
      outv[8 + rg]  = fmaxf(acc2[rg], 0.f);                                    \
      outv[12 + rg] = fmaxf(acc3[rg], 0.f);                                    \
    }                                                                          \
    float s = (((outv[0] + outv[1]) + (outv[2] + outv[3]))                     \
             + ((outv[4] + outv[5]) + (outv[6] + outv[7])))                    \
            + (((outv[8] + outv[9]) + (outv[10] + outv[11]))                   \
             + ((outv[12] + outv[13]) + (outv[14] + outv[15])));               \
    float qa = fmaf(outv[3], outv[3], fmaf(outv[2], outv[2],                   \
               fmaf(outv[1], outv[1], outv[0] * outv[0])));                    \
    float qb = fmaf(outv[7], outv[7], fmaf(outv[6], outv[6],                   \
               fmaf(outv[5], outv[5], outv[4] * outv[4])));                    \
    float qc = fmaf(outv[11], outv[11], fmaf(outv[10], outv[10],               \
               fmaf(outv[9], outv[9], outv[8] * outv[8])));                    \
    float qd = fmaf(outv[15], outv[15], fmaf(outv[14], outv[14],               \
               fmaf(outv[13], outv[13], outv[12] * outv[12])));                \
    float sq = (qa + qb) + (qc + qd);                                          \
    s = red4(s); sq = red4(sq);                                                \
    const float mean = s * 0.015625f;                                          \
    const float var = fmaf(sq, 0.015625f, -mean * mean);                       \
    const float rs = rsqrtf(var + 1e-5f);                                      \
    const float cc = -mean * rs;                                               \
    if (gb) {                                                                  \
      _Pragma("unroll")                                                        \
      for (int mt = 0; mt < 4; ++mt) {                                         \
        float4 gg = *(const float4*)(ln_g + m * 64 + mt * 16 + lg * 4);        \
        float4 bb = *(const float4*)(ln_b + m * 64 + mt * 16 + lg * 4);        \
        outv[mt * 4 + 0] = fmaf(fmaf(outv[mt * 4 + 0], rs, cc), gg.x, bb.x);   \
        outv[mt * 4 + 1] = fmaf(fmaf(outv[mt * 4 + 1], rs, cc), gg.y, bb.y);   \
        outv[mt * 4 + 2] = fmaf(fmaf(outv[mt * 4 + 2], rs, cc), gg.z, bb.z);   \
        outv[mt * 4 + 3] = fmaf(fmaf(outv[mt * 4 + 3], rs, cc), gg.w, bb.w);   \
      }                                                                        \
    } else {                                                                   \
      _Pragma("unroll")                                                        \
      for (int i = 0; i < 16; ++i) outv[i] = fmaf(outv[i], rs, cc);            \
    }                                                                          \
    if (m < 511) {                                                             \
      unsigned Q0 = cvtpk(outv[0], outv[1]),   Q1 = cvtpk(outv[2], outv[3]);   \
      unsigned Q2 = cvtpk(outv[4], outv[5]),   Q3 = cvtpk(outv[6], outv[7]);   \
      unsigned Q4 = cvtpk(outv[8], outv[9]),   Q5 = cvtpk(outv[10], outv[11]); \
      unsigned Q6 = cvtpk(outv[12], outv[13]), Q7 = cvtpk(outv[14], outv[15]); \
      x32<R32>(Q0, Q2); x16<R16>(Q0, Q2);                                      \
      x32<R32>(Q1, Q3); x16<R16>(Q1, Q3);                                      \
      x32<R32>(Q4, Q6); x16<R16>(Q4, Q6);                                      \
      x32<R32>(Q5, Q7); x16<R16>(Q5, Q7);                                      \
      union { unsigned d[4]; short8 s8; } uu0, uu1;                            \
      uu0.d[0] = Q0; uu0.d[1] = Q1; uu0.d[2] = Q2; uu0.d[3] = Q3;              \
      uu1.d[0] = Q4; uu1.d[1] = Q5; uu1.d[2] = Q6; uu1.d[3] = Q7;              \
      hf0 = uu0.s8; hf1 = uu1.s8;                                              \
    }                                                                          \
    asm volatile("s_waitcnt lgkmcnt(8)" ::: "memory");                         \
    __builtin_amdgcn_s_barrier();                                              \
  }

template<bool R16, bool R32>
__device__ void kscan_body(const float* __restrict__ x,
                           const short* __restrict__ wbf,
                           const float* __restrict__ ln_g,
                           const float* __restrict__ ln_b,
                           int gb, float* __restrict__ mem_out,
                           short* __restrict__ wldsb) {
  short (*wlds)[64 * 64] = (short (*)[64 * 64])wldsb;
  const int t = threadIdx.x;
  const int lane = t & 63;
  const int wv = t >> 6;
  const int lcol = lane & 15;
  const int lg = lane >> 4;
  const int blk = blockIdx.x;
  const int r = wv * 16 + lcol;

  const int wsw = (lcol & 7) << 4;
  int wrd[8];
#pragma unroll
  for (int mt = 0; mt < 4; ++mt) {
    wrd[mt * 2]     = mt * 2048 + lcol * 128 + ((lg * 16) ^ wsw);
    wrd[mt * 2 + 1] = mt * 2048 + lcol * 128 + ((lg * 16 + 64) ^ wsw);
  }
  const int so0 = (t * 16) ^ ((((t * 16) >> 7) & 7) << 4);

  short8 hf0, hf1;
  {
    const float4* xr = (const float4*)(x + ((size_t)(blk * 128 + r)) * 64);
    float4 a0 = xr[lg * 2], a1 = xr[lg * 2 + 1];
    float4 b0 = xr[8 + lg * 2], b1 = xr[8 + lg * 2 + 1];
    union { unsigned d[4]; short8 s8; } u0, u1;
    u0.d[0] = cvtpk(a0.x, a0.y); u0.d[1] = cvtpk(a0.z, a0.w);
    u0.d[2] = cvtpk(a1.x, a1.y); u0.d[3] = cvtpk(a1.z, a1.w);
    u1.d[0] = cvtpk(b0.x, b0.y); u1.d[1] = cvtpk(b0.z, b0.w);
    u1.d[2] = cvtpk(b1.x, b1.y); u1.d[3] = cvtpk(b1.z, b1.w);
    hf0 = u0.s8; hf1 = u1.s8;
  }
  {
    int4 w0 = ((const int4*)wbf)[t];
    int4 w1 = ((const int4*)wbf)[512 + t];
    *(int4*)((char*)wlds[0] + so0) = w0;
    *(int4*)((char*)wlds[1] + so0) = w1;
  }
  int4 g0 = ((const int4*)wbf)[1024 + t];
  int4 g1;
  __syncthreads();

  short8 wfA[8], wfB[8];
#pragma unroll
  for (int i = 0; i < 8; ++i) wfA[i] = *(const short8*)((const char*)wlds[0] + wrd[i]);

  const f32x4 z4 = {0.f, 0.f, 0.f, 0.f};
  float outv[16];

  for (int mb = 0; mb < 512; mb += 4) {
    KSTEP(0, wfA, wfB, g0, g1)
    KSTEP(1, wfB, wfA, g1, g0)
    KSTEP(2, wfA, wfB, g0, g1)
    KSTEP(3, wfB, wfA, g1, g0)
  }

  float* mo = mem_out + ((size_t)(blk * 128 + r)) * 64;
#pragma unroll
  for (int mt = 0; mt < 4; ++mt)
    *(float4*)(mo + mt * 16 + lg * 4) =
        make_float4(outv[mt * 4], outv[mt * 4 + 1], outv[mt * 4 + 2], outv[mt * 4 + 3]);
}

__global__ __launch_bounds__(512, 2) void kscan(
    const float* __restrict__ x, const short* __restrict__ wbf,
    const float* __restrict__ ln_g, const float* __restrict__ ln_b,
    const int* __restrict__ flagp, float* __restrict__ mem_out) {
  __shared__ short wlds[4][64 * 64];
  const int lane = threadIdx.x & 63;
  const int gb = *flagp;
  unsigned pa = (unsigned)lane, pb = 1000u + (unsigned)lane;
  pl16raw_ec(pa, pb);
  const bool r16 = (__builtin_amdgcn_readfirstlane((int)pa) != 0);
  unsigned qa = (unsigned)lane, qb = 2000u + (unsigned)lane;
  pl32raw_ec(qa, qb);
  const bool r32 = (__builtin_amdgcn_readfirstlane((int)qa) != 0);
  short* ldsb = &wlds[0][0];
  if (!r16) {
    if (!r32) kscan_body<false, false>(x, wbf, ln_g, ln_b, gb, mem_out, ldsb);
    else      kscan_body<false, true >(x, wbf, ln_g, ln_b, gb, mem_out, ldsb);
  } else {
    if (!r32) kscan_body<true, false >(x, wbf, ln_g, ln_b, gb, mem_out, ldsb);
    else      kscan_body<true, true  >(x, wbf, ln_g, ln_b, gb, mem_out, ldsb);
  }
}

// ---------------- kh/vh via MFMA (main path) ------------------------------
__global__ __launch_bounds__(512) void kkvm(const float* __restrict__ mem_out,
                                            const short* __restrict__ wkv,
                                            const float* __restrict__ beff,
                                            short* __restrict__ khvh) {
  __shared__ short wl[2][64 * 64];
  const int t = threadIdx.x;
  const int lane = t & 63;
  const int wv = t >> 6;
  const int lcol = lane & 15;
  const int lg = lane >> 4;
  const int r = wv * 16 + lcol;
  const int n = blockIdx.x * 128 + r;
  const int wsw = (lcol & 7) << 4;
  int wrd[8];
#pragma unroll
  for (int mt = 0; mt < 4; ++mt) {
    wrd[mt * 2]     = mt * 2048 + lcol * 128 + ((lg * 16) ^ wsw);
    wrd[mt * 2 + 1] = mt * 2048 + lcol * 128 + ((lg * 16 + 64) ^ wsw);
  }
  const int so0 = (t * 16) ^ ((((t * 16) >> 7) & 7) << 4);
  {
    const int4* wp = (const int4*)wkv;
    *(int4*)((char*)wl[0] + so0) = wp[t];          // K-mat (8 KiB)
    *(int4*)((char*)wl[1] + so0) = wp[512 + t];    // V-mat (8 KiB)
  }
  short8 hf0, hf1;
  {
    const float4* xr = (const float4*)(mem_out + (size_t)n * 64);
    float4 a0 = xr[lg * 2], a1 = xr[lg * 2 + 1];
    float4 b0 = xr[8 + lg * 2], b1 = xr[8 + lg * 2 + 1];
    union { unsigned d[4]; short8 s8; } u0, u1;
    u0.d[0] = cvtpk(a0.x, a0.y); u0.d[1] = cvtpk(a0.z, a0.w);
    u0.d[2] = cvtpk(a1.x, a1.y); u0.d[3] = cvtpk(a1.z, a1.w);
    u1.d[0] = cvtpk(b0.x, b0.y); u1.d[1] = cvtpk(b0.z, b0.w);
    u1.d[2] = cvtpk(b1.x, b1.y); u1.d[3] = cvtpk(b1.z, b1.w);
    hf0 = u0.s8; hf1 = u1.s8;
  }
  __syncthreads();
  const f32x4 z4 = {0.f, 0.f, 0.f, 0.f};
  short* row = khvh + (size_t)n * 128;
#pragma unroll
  for (int mt = 0; mt < 4; ++mt) {
    short8 k0 = *(const short8*)((const char*)wl[0] + wrd[mt * 2]);
    short8 k1 = *(const short8*)((const char*)wl[0] + wrd[mt * 2 + 1]);
    f32x4 aK = __builtin_amdgcn_mfma_f32_16x16x32_bf16(k0, hf0, z4, 0, 0, 0);
    aK = __builtin_amdgcn_mfma_f32_16x16x32_bf16(k1, hf1, aK, 0, 0, 0);
    short8 v0 = *(const short8*)((const char*)wl[1] + wrd[mt * 2]);
    short8 v1 = *(const short8*)((const char*)wl[1] + wrd[mt * 2 + 1]);
    f32x4 aV = __builtin_amdgcn_mfma_f32_16x16x32_bf16(v0, hf0, z4, 0, 0, 0);
    aV = __builtin_amdgcn_mfma_f32_16x16x32_bf16(v1, hf1, aV, 0, 0, 0);
    float4 bk = *(const float4*)(beff + 64 + mt * 16 + lg * 4);
    float4 bv = *(const float4*)(beff + 128 + mt * 16 + lg * 4);
    uint2 pk_, pv_;
    pk_.x = cvtpk(aK[0] + bk.x, aK[1] + bk.y);
    pk_.y = cvtpk(aK[2] + bk.z, aK[3] + bk.w);
    pv_.x = cvtpk(aV[0] + bv.x, aV[1] + bv.y);
    pv_.y = cvtpk(aV[2] + bv.z, aV[3] + bv.w);
    *(uint2*)(row + mt * 16 + lg * 4) = pk_;
    *(uint2*)(row + 64 + mt * 16 + lg * 4) = pv_;
  }
}

// ---------------- kh/vh scalar (fallback path only) -----------------------
__global__ __launch_bounds__(256) void kkv(const float* __restrict__ mem_out,
                                           const float* __restrict__ weff,
                                           const float* __restrict__ beff,
                                           short* __restrict__ khvh) {
  __shared__ short kvs[128 * 128];
  const int t = threadIdx.x;
  const int nl = t >> 1;
  const int jh = (t & 1) * 32;
  const int n = blockIdx.x * 128 + nl;
  float mo[64];
  const float4* mop = (const float4*)(mem_out + (size_t)n * 64);
#pragma unroll
  for (int c = 0; c < 16; ++c) {
    float4 f = mop[c];
    mo[c * 4] = f.x; mo[c * 4 + 1] = f.y; mo[c * 4 + 2] = f.z; mo[c * 4 + 3] = f.w;
  }
  const float* wk = weff + 4096;
  const float* wvp = weff + 8192;
  const float* bk = beff + 64;
  const float* bv = beff + 128;
  for (int jj = 0; jj < 32; ++jj) {
    const int j = jh + jj;
    float ak = bk[j], av = bv[j];
    const float* wkr = wk + (size_t)j * 64;
    const float* wvr = wvp + (size_t)j * 64;
#pragma unroll 8
    for (int e = 0; e < 64; ++e) { ak = fmaf(mo[e], wkr[e], ak); av = fmaf(mo[e], wvr[e], av); }
    kvs[nl * 128 + j] = (short)f2bf1(ak);
    kvs[nl * 128 + 64 + j] = (short)f2bf1(av);
  }
  __syncthreads();
  int4* dst = (int4*)(khvh + (size_t)blockIdx.x * 16384);
  const int4* srcl = (const int4*)kvs;
#pragma unroll
  for (int c = 0; c < 8; ++c) dst[t + c * 256] = srcl[t + c * 256];
}

// ---------------- attention, two-stage, bf16 LDS tiles --------------------
__global__ __launch_bounds__(512) void kattn2(const short* __restrict__ khvh,
                                              const float* __restrict__ qh,
                                              float* __restrict__ pO,
                                              float* __restrict__ pE) {
  __shared__ short kv[128 * 128];   // 128-key tile (K|V rows), 32 KiB
  const int t = threadIdx.x;
  const int hh = t >> 6;
  const int ml = t & 63;
  const int c = blockIdx.x >> 2;
  const int mc = blockIdx.x & 3;
  const int m0 = mc * 128 + ml;
  const int m1 = m0 + 64;
  float q0[8], q1[8], o0[8], o1[8];
  float e0 = 0.f, e1 = 0.f;
  {
    const float4* qp0 = (const float4*)(qh + (size_t)m0 * 64 + hh * 8);
    const float4* qp1 = (const float4*)(qh + (size_t)m1 * 64 + hh * 8);
    float4 a = qp0[0], b = qp0[1], cc2 = qp1[0], d2 = qp1[1];
    q0[0]=a.x; q0[1]=a.y; q0[2]=a.z; q0[3]=a.w; q0[4]=b.x; q0[5]=b.y; q0[6]=b.z; q0[7]=b.w;
    q1[0]=cc2.x; q1[1]=cc2.y; q1[2]=cc2.z; q1[3]=cc2.w; q1[4]=d2.x; q1[5]=d2.y; q1[6]=d2.z; q1[7]=d2.w;
#pragma unroll
    for (int d = 0; d < 8; ++d) { o0[d] = 0.f; o1[d] = 0.f; }
  }
  for (int tile = 0; tile < 4; ++tile) {
    if (tile) __syncthreads();
    const int4* src = (const int4*)(khvh + ((size_t)(c * 512 + tile * 128)) * 128);
    int4* dl = (int4*)kv;
#pragma unroll
    for (int u = 0; u < 4; ++u) dl[t + u * 512] = src[t + u * 512];
    __syncthreads();
    for (int n = 0; n < 128; ++n) {
      const short8 kraw = *(const short8*)(kv + n * 128 + hh * 8);
      const short8 vraw = *(const short8*)(kv + n * 128 + 64 + hh * 8);
      float kf[8], vf[8];
#pragma unroll
      for (int d = 0; d < 8; ++d) {
        kf[d] = bf2f((ushort_t)kraw[d]);
        vf[d] = bf2f((ushort_t)vraw[d]);
      }
      float s0 = 0.f, s1 = 0.f;
#pragma unroll
      for (int d = 0; d < 8; ++d) { s0 = fmaf(q0[d], kf[d], s0); s1 = fmaf(q1[d], kf[d], s1); }
      float p0 = __expf(s0), p1 = __expf(s1);
      e0 += p0; e1 += p1;
#pragma unroll
      for (int d = 0; d < 8; ++d) { o0[d] = fmaf(p0, vf[d], o0[d]); o1[d] = fmaf(p1, vf[d], o1[d]); }
    }
  }
  const int idx0 = hh * 512 + m0;
  const int idx1 = hh * 512 + m1;
  pE[(size_t)c * 4096 + idx0] = e0;
  pE[(size_t)c * 4096 + idx1] = e1;
  float4* po0 = (float4*)(pO + (size_t)c * 32768 + (size_t)idx0 * 8);
  float4* po1 = (float4*)(pO + (size_t)c * 32768 + (size_t)idx1 * 8);
  po0[0] = make_float4(o0[0], o0[1], o0[2], o0[3]);
  po0[1] = make_float4(o0[4], o0[5], o0[6], o0[7]);
  po1[0] = make_float4(o1[0], o1[1], o1[2], o1[3]);
  po1[1] = make_float4(o1[4], o1[5], o1[6], o1[7]);
}

// ---------------- attention fallback (atomics) if ws too small ----------
__global__ __launch_bounds__(512) void kattn_atomic(const short* __restrict__ khvh,
                                                    const float* __restrict__ qh,
                                                    float* __restrict__ oacc,
                                                    float* __restrict__ esum) {
  __shared__ short kv[128 * 128];
  const int t = threadIdx.x;
  const int hh = t >> 6;
  const int ms = t & 63;
  {
    const int4* src = (const int4*)(khvh + (size_t)blockIdx.x * 16384);
    int4* d = (int4*)kv;
#pragma unroll
    for (int c = 0; c < 4; ++c) d[t + c * 512] = src[t + c * 512];
  }
  __syncthreads();
  float q[8][8], o[8][8], es[8];
#pragma unroll
  for (int i = 0; i < 8; ++i) {
    const float4* qp = (const float4*)(qh + ((size_t)(ms + i * 64)) * 64 + hh * 8);
    float4 q0 = qp[0], q1 = qp[1];
    q[i][0] = q0.x; q[i][1] = q0.y; q[i][2] = q0.z; q[i][3] = q0.w;
    q[i][4] = q1.x; q[i][5] = q1.y; q[i][6] = q1.z; q[i][7] = q1.w;
    es[i] = 0.f;
#pragma unroll
    for (int d = 0; d < 8; ++d) o[i][d] = 0.f;
  }
  for (int n = 0; n < 128; ++n) {
    const short8 kraw = *(const short8*)(kv + n * 128 + hh * 8);
    const short8 vraw = *(const short8*)(kv + n * 128 + 64 + hh * 8);
    float kf[8], vf[8];
#pragma unroll
    for (int d = 0; d < 8; ++d) {
      kf[d] = bf2f((ushort_t)kraw[d]);
      vf[d] = bf2f((ushort_t)vraw[d]);
    }
#pragma unroll
    for (int i = 0; i < 8; ++i) {
      float s = 0.f;
#pragma unroll
      for (int d = 0; d < 8; ++d) s = fmaf(q[i][d], kf[d], s);
      float p = __expf(s);
      es[i] += p;
#pragma unroll
      for (int d = 0; d < 8; ++d) o[i][d] = fmaf(p, vf[d], o[i][d]);
    }
  }
#pragma unroll
  for (int i = 0; i < 8; ++i) {
    const int m = ms + i * 64;
    atomicAdd(&esum[hh * 512 + m], es[i]);
#pragma unroll
    for (int d = 0; d < 8; ++d) atomicAdd(&oacc[((size_t)(hh * 512 + m)) * 8 + d], o[i][d]);
  }
}

// ---------------- fused chunk-reduce + ratio + final (main path) ----------
__global__ __launch_bounds__(256) void kfr2(const float* __restrict__ pO,
                                            const float* __restrict__ pE,
                                            const float* __restrict__ out_w,
                                            const float* __restrict__ out_b,
                                            const float* __restrict__ avg,
                                            const float* __restrict__ mem_w,
                                            float* __restrict__ out1) {
  __shared__ float ored[64];
  __shared__ float ered[8];
  __shared__ float rat[64];
  const int t = threadIdx.x;
  const int m = blockIdx.x;
  if (t < 64) {
    int h = t >> 3, d = t & 7;
    float s = 0.f;
#pragma unroll 8
    for (int c = 0; c < NCH; ++c)
      s += pO[(size_t)c * 32768 + ((size_t)(h * 512 + m)) * 8 + d];
    ored[t] = s;
  } else if (t < 72) {
    int h = t - 64;
    float s = 0.f;
#pragma unroll 8
    for (int c = 0; c < NCH; ++c)
      s += pE[(size_t)c * 4096 + h * 512 + m];
    ered[h] = s;
  }
  __syncthreads();
  if (t < 64) {
    const int e = t;
    float inv[8];
#pragma unroll
    for (int h = 0; h < 8; ++h) inv[h] = 1.f / ered[h];
    float a = out_b[e];
    const float* wr = out_w + (size_t)e * 64;
#pragma unroll
    for (int j = 0; j < 64; ++j) a = fmaf(ored[j] * inv[j >> 3], wr[j], a);
    rat[e] = 1.f + a / avg[m * 64 + e];
  }
  __syncthreads();
  const float4* src = (const float4*)(mem_w + (size_t)m * 4096);
  float4* dst = (float4*)(out1 + (size_t)m * 4096);
#pragma unroll
  for (int c = 0; c < 4; ++c) {
    int idx = t + c * 256;
    float rr = rat[idx >> 4];
    float4 w = src[idx];
    dst[idx] = make_float4(w.x * rr, w.y * rr, w.z * rr, w.w * rr);
  }
}

// ---------------- ratio + final from oacc/esum (fallback path) ------------
__global__ __launch_bounds__(256) void kfr(const float* __restrict__ oacc,
                                           const float* __restrict__ esum,
                                           const float* __restrict__ out_w,
                                           const float* __restrict__ out_b,
                                           const float* __restrict__ avg,
                                           const float* __restrict__ mem_w,
                                           float* __restrict__ out1) {
  __shared__ float rat[64];
  const int t = threadIdx.x;
  const int m = blockIdx.x;
  if (t < 64) {
    const int e = t;
    float of[64];
#pragma unroll
    for (int h = 0; h < 8; ++h) {
      float inv = 1.f / esum[h * 512 + m];
      const float* op = oacc + ((size_t)(h * 512 + m)) * 8;
#pragma unroll
      for (int d = 0; d < 8; ++d) of[h * 8 + d] = op[d] * inv;
    }
    float a = out_b[e];
    const float* wr = out_w + (size_t)e * 64;
#pragma unroll 8
    for (int j = 0; j < 64; ++j) a = fmaf(of[j], wr[j], a);
    rat[e] = 1.f + a / avg[m * 64 + e];
  }
  __syncthreads();
  const float4* src = (const float4*)(mem_w + (size_t)m * 4096);
  float4* dst = (float4*)(out1 + (size_t)m * 4096);
#pragma unroll
  for (int c = 0; c < 4; ++c) {
    int idx = t + c * 256;
    float rr = rat[idx >> 4];
    float4 w = src[idx];
    dst[idx] = make_float4(w.x * rr, w.y * rr, w.z * rr, w.w * rr);
  }
}

extern "C" void kernel_launch(void* const* d_in, const int* in_sizes, int n_in,
                              void* d_out, int out_size, void* d_ws, size_t ws_size,
                              hipStream_t stream) {
  (void)in_sizes; (void)n_in; (void)out_size;
  const float* x         = (const float*)d_in[0];
  const float* mem_w     = (const float*)d_in[1];
  const float* ln_g      = (const float*)d_in[2];
  const float* ln_b      = (const float*)d_in[3];
  const float* Wq        = (const float*)d_in[4];
  const float* bq        = (const float*)d_in[5];
  const float* Wk        = (const float*)d_in[6];
  const float* bk        = (const float*)d_in[7];
  const float* Wv        = (const float*)d_in[8];
  const float* bv        = (const float*)d_in[9];
  const float* in_proj_w = (const float*)d_in[10];
  const float* in_proj_b = (const float*)d_in[11];
  const float* out_w     = (const float*)d_in[12];
  const float* out_b     = (const float*)d_in[13];

  float* dout = (float*)d_out;
  char* ws = (char*)d_ws;
  short* wbf   = (short*)(ws + WBF_OFF);
  short* khvh  = (short*)(ws + KVH_OFF);
  float* qh    = (float*)(ws + QH_OFF);
  float* avg   = (float*)(ws + AVG_OFF);
  float* weff  = (float*)(ws + WEFF_OFF);
  float* beff  = (float*)(ws + BEFF_OFF);
  float* oacc  = (float*)(ws + OACC_OFF);
  float* esum  = (float*)(ws + ESUM_OFF);
  int*   flag  = (int*)(ws + FLAG_OFF);
  float* pO    = (float*)(ws + PO_OFF);
  float* pE    = (float*)(ws + PE_OFF);
  short* wkv   = (short*)(ws + WKV_OFF);

  float* mem_out = dout;              // output 0: (32768, 64)
  float* out1    = dout + 2097152;    // output 1: (512, 64, 64)

  const bool use_part = (ws_size >= WS_NEED);   // host-constant: graph-safe

  hipMemsetAsync(flag, 0, 4, stream);
  kpre<<<305, 256, 0, stream>>>(mem_w, ln_g, ln_b, in_proj_w, in_proj_b,
                                Wq, bq, Wk, bk, Wv, bv, wbf, avg, weff, beff,
                                wkv, flag);
  kqh<<<128, 256, 0, stream>>>(avg, weff, beff, qh);
  kscan<<<256, 512, 0, stream>>>(x, wbf, ln_g, ln_b, flag, mem_out);
  if (use_part) {
    kkvm<<<256, 512, 0, stream>>>(mem_out, wkv, beff, khvh);
    kattn2<<<NCH * 4, 512, 0, stream>>>(khvh, qh, pO, pE);
    kfr2<<<512, 256, 0, stream>>>(pO, pE, out_w, out_b, avg, mem_w, out1);
  } else {
    kkv<<<256, 256, 0, stream>>>(mem_out, weff, beff, khvh);
    kinit<<<144, 256, 0, stream>>>(oacc);
    kattn_atomic<<<256, 512, 0, stream>>>(khvh, qh, oacc, esum);
    kfr<<<512, 256, 0, stream>>>(oacc, esum, out_w, out_b, avg, mem_w, out1);
  }
}